// Round 3
// baseline (527.040 us; speedup 1.0000x reference)
//
#include <hip/hip_runtime.h>
#include <math.h>

#define NSNPS  500000
#define NGENES 20000
#define NNODES 600000
#define NEDGES 320000
#define BB     16
#define NFILT  8

// rsqrt(1 + 1e-5)
#define BN_SCALE 0.99999500003749968f

__device__ __forceinline__ float gelu_erf(float x) {
    return 0.5f * x * (1.0f + erff(x * 0.70710678118654752f));
}
__device__ __forceinline__ float sigmoidf_(float x) {
    return 1.0f / (1.0f + expf(-x));
}

// ---------------------------------------------------------------------------
// filters [NFILT, NSNPS] -> filtersT [NSNPS, NFILT]
__global__ __launch_bounds__(256) void k_transpose(const float* __restrict__ filters,
                                                   float* __restrict__ filtersT) {
    int idx = blockIdx.x * 256 + threadIdx.x;
    if (idx >= NFILT * NSNPS) return;
    int f = idx / NSNPS;
    int n = idx - f * NSNPS;
    filtersT[n * NFILT + f] = filters[idx];
}

// ---------------------------------------------------------------------------
// snp [BB, NSNPS] -> snpT [NSNPS, BB]
__global__ __launch_bounds__(256) void k_snpT(const float* __restrict__ snp,
                                              float* __restrict__ snpT) {
    int n = blockIdx.x * 256 + threadIdx.x;
    if (n >= NSNPS) return;
    float v[16];
    #pragma unroll
    for (int b = 0; b < 16; b++) v[b] = snp[(size_t)b * NSNPS + n];
    float4* dst = (float4*)(snpT + (size_t)n * 16);
    dst[0] = make_float4(v[0], v[1], v[2], v[3]);
    dst[1] = make_float4(v[4], v[5], v[6], v[7]);
    dst[2] = make_float4(v[8], v[9], v[10], v[11]);
    dst[3] = make_float4(v[12], v[13], v[14], v[15]);
}

// ---------------------------------------------------------------------------
__global__ __launch_bounds__(256) void k_node_off(const int* __restrict__ gene_of_node,
                                                  int* __restrict__ node_off) {
    int g = blockIdx.x * 256 + threadIdx.x;
    if (g > NGENES) return;
    int lo = 0, hi = NNODES;
    while (lo < hi) {
        int mid = (lo + hi) >> 1;
        if (gene_of_node[mid] < g) lo = mid + 1; else hi = mid;
    }
    node_off[g] = lo;
}

// ---------------------------------------------------------------------------
__global__ __launch_bounds__(256) void k_zero(int* __restrict__ deg, float* __restrict__ g_h) {
    int i = blockIdx.x * 256 + threadIdx.x;
    if (i < NGENES) deg[i] = 0;
    if (i < BB * NFILT) g_h[i] = 0.0f;
}

__global__ __launch_bounds__(256) void k_deg(const int* __restrict__ edge_dst,
                                             int* __restrict__ deg) {
    int e = blockIdx.x * 256 + threadIdx.x;
    if (e >= NEDGES) return;
    atomicAdd(&deg[edge_dst[e]], 1);
}

__global__ __launch_bounds__(1024) void k_scan(const int* __restrict__ deg,
                                               int* __restrict__ csr_off,
                                               int* __restrict__ cursor) {
    __shared__ int sums[1024];
    int t = threadIdx.x;
    const int CH = (NGENES + 1023) / 1024;   // 20
    int base = t * CH;
    int s = 0;
    for (int i = 0; i < CH; i++) {
        int idx = base + i;
        if (idx < NGENES) s += deg[idx];
    }
    sums[t] = s;
    __syncthreads();
    for (int off = 1; off < 1024; off <<= 1) {
        int v = (t >= off) ? sums[t - off] : 0;
        __syncthreads();
        sums[t] += v;
        __syncthreads();
    }
    int run = (t == 0) ? 0 : sums[t - 1];
    for (int i = 0; i < CH; i++) {
        int idx = base + i;
        if (idx < NGENES) {
            csr_off[idx] = run;
            cursor[idx]  = run;
            run += deg[idx];
        }
    }
    if (t == 1023) csr_off[NGENES] = sums[1023];
}

__global__ __launch_bounds__(256) void k_scatter(const int* __restrict__ edge_src,
                                                 const int* __restrict__ edge_dst,
                                                 int* __restrict__ cursor,
                                                 int* __restrict__ csr_src) {
    int e = blockIdx.x * 256 + threadIdx.x;
    if (e >= NEDGES) return;
    int p = atomicAdd(&cursor[edge_dst[e]], 1);
    csr_src[p] = edge_src[e];
}

// ---------------------------------------------------------------------------
// v3: one wave per gene, gene-major output h_gm[g][b*8+f].
// lane = sub*16 + b (sub = node slot 0..3, b = batch). Each lane accumulates
// all 8 filters for its batch; final reduce over sub via 2 shuffles.
__global__ __launch_bounds__(256) void k_snp2gene_v3(const float* __restrict__ snpT,
                                                     const int* __restrict__ snp_ids,
                                                     const int* __restrict__ node_off,
                                                     const float* __restrict__ filtersT,
                                                     float* __restrict__ h_gm) {
    int wave = threadIdx.x >> 6, lane = threadIdx.x & 63;
    int g = blockIdx.x * 4 + wave;
    int sub = lane >> 4;
    int b = lane & 15;
    int s = node_off[g], e = node_off[g + 1];
    float acc[8];
    #pragma unroll
    for (int f = 0; f < 8; f++) acc[f] = 0.0f;
    for (int i = s + sub; i < e; i += 4) {
        int sid = snp_ids[i];
        float val = snpT[(size_t)sid * 16 + b];
        float4 fa = *(const float4*)(filtersT + (size_t)sid * 8);
        float4 fb = *(const float4*)(filtersT + (size_t)sid * 8 + 4);
        acc[0] += val * fa.x; acc[1] += val * fa.y; acc[2] += val * fa.z; acc[3] += val * fa.w;
        acc[4] += val * fb.x; acc[5] += val * fb.y; acc[6] += val * fb.z; acc[7] += val * fb.w;
    }
    #pragma unroll
    for (int f = 0; f < 8; f++) {
        acc[f] += __shfl_xor(acc[f], 16, 64);
        acc[f] += __shfl_xor(acc[f], 32, 64);
    }
    if (lane < 16) {   // lane == b
        float* dst = h_gm + (size_t)g * 128 + lane * 8;
        *(float4*)(dst)     = make_float4(acc[0], acc[1], acc[2], acc[3]);
        *(float4*)(dst + 4) = make_float4(acc[4], acc[5], acc[6], acc[7]);
    }
}

// ---------------------------------------------------------------------------
// GIN layer, gene-major: one wave per gene. Per edge: ONE coalesced 512B load
// covers all 16 batches (float2 per lane, lane = b*4 + fpair).
// MLP done by wave 0 after LDS roundtrip (64 rows = 4 genes x 16 batches).
// out_batch_major: layer-2 writes batch-major so k_readout stays coalesced.
__global__ __launch_bounds__(256) void k_gin_gm(const float* __restrict__ hin,   // [g][128]
                                                float* __restrict__ hout,
                                                const int* __restrict__ csr_off,
                                                const int* __restrict__ csr_src,
                                                const float* __restrict__ eps_l,
                                                const float* __restrict__ W1,
                                                const float* __restrict__ b1,
                                                const float* __restrict__ g1,
                                                const float* __restrict__ bt1,
                                                const float* __restrict__ W2,
                                                const float* __restrict__ b2,
                                                const float* __restrict__ g2,
                                                const float* __restrict__ bt2,
                                                int out_batch_major) {
    __shared__ float sW1[128], sb1[16], sg1[16], sbt1[16];
    __shared__ float sW2[128], sb2[8], sg2[8], sbt2[8];
    __shared__ float sZ[4][128];
    int t = threadIdx.x;
    if (t < 128) { sW1[t] = W1[t]; sW2[t] = W2[t]; }
    if (t < 16)  { sb1[t] = b1[t]; sg1[t] = g1[t]; sbt1[t] = bt1[t]; }
    if (t < 8)   { sb2[t] = b2[t]; sg2[t] = g2[t]; sbt2[t] = bt2[t]; }

    int wave = t >> 6, lane = t & 63;
    int g = blockIdx.x * 4 + wave;
    float epsv = 1.0f + eps_l[0];
    float2 acc = *(const float2*)(hin + (size_t)g * 128 + lane * 2);
    acc.x *= epsv; acc.y *= epsv;

    int s = csr_off[g], e = csr_off[g + 1];
    for (int base = s; base < e; base += 64) {
        int myid = (base + lane < e) ? csr_src[base + lane] : 0;
        int n = e - base; if (n > 64) n = 64;
        for (int j = 0; j < n; j++) {
            int sid = __shfl(myid, j, 64);
            float2 v = *(const float2*)(hin + (size_t)sid * 128 + lane * 2);
            acc.x += v.x; acc.y += v.y;
        }
    }
    *(float2*)(&sZ[wave][lane * 2]) = acc;
    __syncthreads();

    if (t < 64) {
        int gs = t >> 4, b = t & 15;
        int gg = blockIdx.x * 4 + gs;
        float z[8];
        #pragma unroll
        for (int i = 0; i < 8; i++) z[i] = sZ[gs][b * 8 + i];
        float o[8];
        #pragma unroll
        for (int f = 0; f < 8; f++) o[f] = sb2[f];
        #pragma unroll
        for (int j = 0; j < 16; j++) {
            float s1 = sb1[j];
            #pragma unroll
            for (int i = 0; i < 8; i++) s1 += z[i] * sW1[i * 16 + j];
            s1 = s1 * BN_SCALE * sg1[j] + sbt1[j];
            s1 = gelu_erf(s1);
            #pragma unroll
            for (int f = 0; f < 8; f++) o[f] += s1 * sW2[j * 8 + f];
        }
        float r[8];
        #pragma unroll
        for (int f = 0; f < 8; f++) {
            float v = o[f] * BN_SCALE * sg2[f] + sbt2[f];
            r[f] = gelu_erf(v);
        }
        float* ho = out_batch_major ? hout + ((size_t)b * NGENES + gg) * 8
                                    : hout + (size_t)gg * 128 + b * 8;
        *(float4*)(ho)     = make_float4(r[0], r[1], r[2], r[3]);
        *(float4*)(ho + 4) = make_float4(r[4], r[5], r[6], r[7]);
    }
}

// ---------------------------------------------------------------------------
// Attentive readout on batch-major h: w = sigmoid((h@Wk+bk)@Wq); g_h += (h@Wv+bv)*w
__global__ __launch_bounds__(256) void k_readout(const float* __restrict__ h,
                                                 const float* __restrict__ Wk,
                                                 const float* __restrict__ bk,
                                                 const float* __restrict__ Wq,
                                                 const float* __restrict__ Wv,
                                                 const float* __restrict__ bv,
                                                 float* __restrict__ w_out,
                                                 float* __restrict__ g_h) {
    __shared__ float sWk[64], sWv[64], sbk[8], sbv[8], sWq[8];
    __shared__ float lds[4][8];
    int t = threadIdx.x;
    if (t < 64) { sWk[t] = Wk[t]; sWv[t] = Wv[t]; }
    if (t < 8)  { sbk[t] = bk[t]; sbv[t] = bv[t]; sWq[t] = Wq[t]; }
    __syncthreads();

    int g = blockIdx.x * 256 + t;
    int b = blockIdx.y;
    float contrib[8];
    #pragma unroll
    for (int f = 0; f < 8; f++) contrib[f] = 0.0f;

    if (g < NGENES) {
        const float* hr = h + ((size_t)b * NGENES + g) * NFILT;
        float hv[8];
        #pragma unroll
        for (int i = 0; i < 8; i++) hv[i] = hr[i];
        float q = 0.0f;
        #pragma unroll
        for (int j = 0; j < 8; j++) {
            float key = sbk[j];
            #pragma unroll
            for (int i = 0; i < 8; i++) key += hv[i] * sWk[i * 8 + j];
            q += key * sWq[j];
        }
        float w = sigmoidf_(q);
        w_out[(size_t)b * NGENES + g] = w;
        #pragma unroll
        for (int f = 0; f < 8; f++) {
            float v = sbv[f];
            #pragma unroll
            for (int i = 0; i < 8; i++) v += hv[i] * sWv[i * 8 + f];
            contrib[f] = v * w;
        }
    }
    #pragma unroll
    for (int f = 0; f < 8; f++) {
        #pragma unroll
        for (int m = 1; m < 64; m <<= 1) contrib[f] += __shfl_xor(contrib[f], m, 64);
    }
    int wave = t >> 6, lane = t & 63;
    if (lane < 8) lds[wave][lane] = contrib[lane];
    __syncthreads();
    if (t < 8) {
        float s = lds[0][t] + lds[1][t] + lds[2][t] + lds[3][t];
        atomicAdd(&g_h[b * NFILT + t], s);
    }
}

// ---------------------------------------------------------------------------
__global__ __launch_bounds__(1024) void k_head(const float* __restrict__ g_h,
                                               const float* __restrict__ Wp1, const float* __restrict__ bp1,
                                               const float* __restrict__ gp1, const float* __restrict__ btp1,
                                               const float* __restrict__ Wp2, const float* __restrict__ bp2,
                                               const float* __restrict__ gp2, const float* __restrict__ btp2,
                                               const float* __restrict__ Wp3, const float* __restrict__ bp3,
                                               float* __restrict__ preds) {
    __shared__ float sgh[128];
    __shared__ float z1[16 * 64];
    __shared__ float z2[16 * 16];
    int t = threadIdx.x;
    if (t < 128) sgh[t] = g_h[t];
    __syncthreads();
    {
        int b = t >> 6, j = t & 63;
        float s = bp1[j];
        #pragma unroll
        for (int k = 0; k < 8; k++) s += sgh[b * 8 + k] * Wp1[k * 64 + j];
        s = s * BN_SCALE * gp1[j] + btp1[j];
        z1[b * 64 + j] = gelu_erf(s);
    }
    __syncthreads();
    if (t < 256) {
        int b = t >> 4, j = t & 15;
        float s = bp2[j];
        for (int k = 0; k < 64; k++) s += z1[b * 64 + k] * Wp2[k * 16 + j];
        s = s * BN_SCALE * gp2[j] + btp2[j];
        z2[b * 16 + j] = gelu_erf(s);
    }
    __syncthreads();
    if (t < 16) {
        float s = bp3[0];
        #pragma unroll
        for (int k = 0; k < 16; k++) s += z2[t * 16 + k] * Wp3[k];
        preds[t] = s;
    }
}

// ---------------------------------------------------------------------------
__global__ __launch_bounds__(256) void k_copy4(const float4* __restrict__ src,
                                               float4* __restrict__ dst, int n4) {
    int i = blockIdx.x * 256 + threadIdx.x;
    if (i < n4) dst[i] = src[i];
}

// ---------------------------------------------------------------------------
extern "C" void kernel_launch(void* const* d_in, const int* in_sizes, int n_in,
                              void* d_out, int out_size, void* d_ws, size_t ws_size,
                              hipStream_t stream) {
    const float* snp          = (const float*)d_in[0];
    const int*   snp_ids      = (const int*)  d_in[1];
    const int*   gene_of_node = (const int*)  d_in[2];
    const int*   edge_src     = (const int*)  d_in[3];
    const int*   edge_dst     = (const int*)  d_in[4];
    const float* filters      = (const float*)d_in[5];
    const float* eps          = (const float*)d_in[6];
    const float* W1  = (const float*)d_in[7];
    const float* b1  = (const float*)d_in[8];
    const float* g1  = (const float*)d_in[9];
    const float* bt1 = (const float*)d_in[10];
    const float* W2  = (const float*)d_in[11];
    const float* b2  = (const float*)d_in[12];
    const float* g2  = (const float*)d_in[13];
    const float* bt2 = (const float*)d_in[14];
    const float* Wk  = (const float*)d_in[15];
    const float* bk  = (const float*)d_in[16];
    const float* Wq  = (const float*)d_in[17];
    const float* Wv  = (const float*)d_in[18];
    const float* bv  = (const float*)d_in[19];
    const float* Wp1 = (const float*)d_in[20];
    const float* bp1 = (const float*)d_in[21];
    const float* gp1 = (const float*)d_in[22];
    const float* btp1= (const float*)d_in[23];
    const float* Wp2 = (const float*)d_in[24];
    const float* bp2 = (const float*)d_in[25];
    const float* gp2 = (const float*)d_in[26];
    const float* btp2= (const float*)d_in[27];
    const float* Wp3 = (const float*)d_in[28];
    const float* bp3 = (const float*)d_in[29];

    float* out        = (float*)d_out;
    float* out_preds  = out;
    float* out_filt   = out + 16;
    float* out_w      = out + 16 + NFILT * NSNPS;

    // filtersT scratch lives in the d_out filters region (16 MB), overwritten
    // by the real filters copy at the very end.
    float* filtersT = out_filt;

    // ---- workspace layout. snpT (32 MB) is dead after snp2gene; h1_gm and
    // h2_bm alias disjoint parts of it (10.24 MB each, written afterwards).
    char* ws = (char*)d_ws;
    size_t off = 0;
    float* h0_gm = (float*)(ws + off); off += (size_t)BB * NGENES * NFILT * 4;  // 10.24 MB
    float* snpT  = (float*)(ws + off);
    float* h1_gm = snpT;                                                        // alias (disjoint in time)
    float* h2_bm = snpT + (size_t)BB * NGENES * NFILT;                          // alias, next 10.24 MB
    off += (size_t)NSNPS * BB * 4;                                              // 32 MB
    int* node_off = (int*)(ws + off); off += ((NGENES + 1) * 4 + 255) / 256 * 256;
    int* deg      = (int*)(ws + off); off += (NGENES * 4 + 255) / 256 * 256;
    int* csr_off  = (int*)(ws + off); off += ((NGENES + 1) * 4 + 255) / 256 * 256;
    int* cursor   = (int*)(ws + off); off += (NGENES * 4 + 255) / 256 * 256;
    int* csr_src  = (int*)(ws + off); off += (size_t)NEDGES * 4;
    float* g_h    = (float*)(ws + off); off += 256;

    // 1. transposes
    k_transpose<<<(NFILT * NSNPS + 255) / 256, 256, 0, stream>>>(filters, filtersT);
    k_snpT<<<(NSNPS + 255) / 256, 256, 0, stream>>>(snp, snpT);
    // 2. gene node offsets
    k_node_off<<<(NGENES + 1 + 255) / 256, 256, 0, stream>>>(gene_of_node, node_off);
    // 3. CSR build
    k_zero<<<(NGENES + 255) / 256, 256, 0, stream>>>(deg, g_h);
    k_deg<<<(NEDGES + 255) / 256, 256, 0, stream>>>(edge_dst, deg);
    k_scan<<<1, 1024, 0, stream>>>(deg, csr_off, cursor);
    k_scatter<<<(NEDGES + 255) / 256, 256, 0, stream>>>(edge_src, edge_dst, cursor, csr_src);
    // 4. SNP -> gene readout (gene-major output)
    k_snp2gene_v3<<<NGENES / 4, 256, 0, stream>>>(snpT, snp_ids, node_off, filtersT, h0_gm);
    // 5. GIN layers (wave-per-gene; layer 2 emits batch-major for readout)
    k_gin_gm<<<NGENES / 4, 256, 0, stream>>>(h0_gm, h1_gm, csr_off, csr_src, eps + 0,
                                             W1 + 0 * 128, b1 + 0 * 16, g1 + 0 * 16, bt1 + 0 * 16,
                                             W2 + 0 * 128, b2 + 0 * 8, g2 + 0 * 8, bt2 + 0 * 8, 0);
    k_gin_gm<<<NGENES / 4, 256, 0, stream>>>(h1_gm, h2_bm, csr_off, csr_src, eps + 1,
                                             W1 + 1 * 128, b1 + 1 * 16, g1 + 1 * 16, bt1 + 1 * 16,
                                             W2 + 1 * 128, b2 + 1 * 8, g2 + 1 * 8, bt2 + 1 * 8, 1);
    // 6. attentive readout (batch-major input, unchanged)
    dim3 grid_row((NGENES + 255) / 256, BB);
    k_readout<<<grid_row, 256, 0, stream>>>(h2_bm, Wk, bk, Wq, Wv, bv, out_w, g_h);
    // 7. head MLP
    k_head<<<1, 1024, 0, stream>>>(g_h, Wp1, bp1, gp1, btp1, Wp2, bp2, gp2, btp2, Wp3, bp3, out_preds);
    // 8. filters passthrough (overwrites filtersT scratch)
    k_copy4<<<(NFILT * NSNPS / 4 + 255) / 256, 256, 0, stream>>>((const float4*)filters,
                                                                 (float4*)out_filt,
                                                                 NFILT * NSNPS / 4);
}

// Round 4
// 429.315 us; speedup vs baseline: 1.2276x; 1.2276x over previous
//
#include <hip/hip_runtime.h>
#include <math.h>

#define NSNPS  500000
#define NGENES 20000
#define NNODES 600000
#define NEDGES 320000
#define BB     16
#define NFILT  8

// rsqrt(1 + 1e-5)
#define BN_SCALE 0.99999500003749968f

__device__ __forceinline__ float gelu_erf(float x) {
    return 0.5f * x * (1.0f + erff(x * 0.70710678118654752f));
}
__device__ __forceinline__ float sigmoidf_(float x) {
    return 1.0f / (1.0f + expf(-x));
}

// ---------------------------------------------------------------------------
// filters [NFILT, NSNPS] -> filtersT [NSNPS, NFILT]
__global__ __launch_bounds__(256) void k_transpose(const float* __restrict__ filters,
                                                   float* __restrict__ filtersT) {
    int idx = blockIdx.x * 256 + threadIdx.x;
    if (idx >= NFILT * NSNPS) return;
    int f = idx / NSNPS;
    int n = idx - f * NSNPS;
    filtersT[n * NFILT + f] = filters[idx];
}

// ---------------------------------------------------------------------------
// snp [BB, NSNPS] -> snpT [NSNPS, BB]
__global__ __launch_bounds__(256) void k_snpT(const float* __restrict__ snp,
                                              float* __restrict__ snpT) {
    int n = blockIdx.x * 256 + threadIdx.x;
    if (n >= NSNPS) return;
    float v[16];
    #pragma unroll
    for (int b = 0; b < 16; b++) v[b] = snp[(size_t)b * NSNPS + n];
    float4* dst = (float4*)(snpT + (size_t)n * 16);
    dst[0] = make_float4(v[0], v[1], v[2], v[3]);
    dst[1] = make_float4(v[4], v[5], v[6], v[7]);
    dst[2] = make_float4(v[8], v[9], v[10], v[11]);
    dst[3] = make_float4(v[12], v[13], v[14], v[15]);
}

// ---------------------------------------------------------------------------
__global__ __launch_bounds__(256) void k_node_off(const int* __restrict__ gene_of_node,
                                                  int* __restrict__ node_off) {
    int g = blockIdx.x * 256 + threadIdx.x;
    if (g > NGENES) return;
    int lo = 0, hi = NNODES;
    while (lo < hi) {
        int mid = (lo + hi) >> 1;
        if (gene_of_node[mid] < g) lo = mid + 1; else hi = mid;
    }
    node_off[g] = lo;
}

// ---------------------------------------------------------------------------
__global__ __launch_bounds__(256) void k_zero(int* __restrict__ deg, float* __restrict__ g_h) {
    int i = blockIdx.x * 256 + threadIdx.x;
    if (i < NGENES) deg[i] = 0;
    if (i < BB * NFILT) g_h[i] = 0.0f;
}

__global__ __launch_bounds__(256) void k_deg(const int* __restrict__ edge_dst,
                                             int* __restrict__ deg) {
    int e = blockIdx.x * 256 + threadIdx.x;
    if (e >= NEDGES) return;
    atomicAdd(&deg[edge_dst[e]], 1);
}

__global__ __launch_bounds__(1024) void k_scan(const int* __restrict__ deg,
                                               int* __restrict__ csr_off,
                                               int* __restrict__ cursor) {
    __shared__ int sums[1024];
    int t = threadIdx.x;
    const int CH = (NGENES + 1023) / 1024;   // 20
    int base = t * CH;
    int s = 0;
    for (int i = 0; i < CH; i++) {
        int idx = base + i;
        if (idx < NGENES) s += deg[idx];
    }
    sums[t] = s;
    __syncthreads();
    for (int off = 1; off < 1024; off <<= 1) {
        int v = (t >= off) ? sums[t - off] : 0;
        __syncthreads();
        sums[t] += v;
        __syncthreads();
    }
    int run = (t == 0) ? 0 : sums[t - 1];
    for (int i = 0; i < CH; i++) {
        int idx = base + i;
        if (idx < NGENES) {
            csr_off[idx] = run;
            cursor[idx]  = run;
            run += deg[idx];
        }
    }
    if (t == 1023) csr_off[NGENES] = sums[1023];
}

__global__ __launch_bounds__(256) void k_scatter(const int* __restrict__ edge_src,
                                                 const int* __restrict__ edge_dst,
                                                 int* __restrict__ cursor,
                                                 int* __restrict__ csr_src) {
    int e = blockIdx.x * 256 + threadIdx.x;
    if (e >= NEDGES) return;
    int p = atomicAdd(&cursor[edge_dst[e]], 1);
    csr_src[p] = edge_src[e];
}

// ---------------------------------------------------------------------------
// v4: one wave per gene, unrolled x4 (16 nodes per wave-iteration).
// lane = sub*16 + b. Gene-major output h_gm[g][b*8+f].
__global__ __launch_bounds__(256) void k_snp2gene_v4(const float* __restrict__ snpT,
                                                     const int* __restrict__ snp_ids,
                                                     const int* __restrict__ node_off,
                                                     const float* __restrict__ filtersT,
                                                     float* __restrict__ h_gm) {
    int wave = threadIdx.x >> 6, lane = threadIdx.x & 63;
    int g = blockIdx.x * 4 + wave;
    int sub = lane >> 4;
    int b = lane & 15;
    int s = node_off[g], e = node_off[g + 1];
    float acc[8];
    #pragma unroll
    for (int f = 0; f < 8; f++) acc[f] = 0.0f;

    int i = s + sub;
    for (; i + 12 < e; i += 16) {
        int id0 = snp_ids[i];
        int id1 = snp_ids[i + 4];
        int id2 = snp_ids[i + 8];
        int id3 = snp_ids[i + 12];
        float v0 = snpT[(size_t)id0 * 16 + b];
        float v1 = snpT[(size_t)id1 * 16 + b];
        float v2 = snpT[(size_t)id2 * 16 + b];
        float v3 = snpT[(size_t)id3 * 16 + b];
        float4 a0 = *(const float4*)(filtersT + (size_t)id0 * 8);
        float4 b0 = *(const float4*)(filtersT + (size_t)id0 * 8 + 4);
        float4 a1 = *(const float4*)(filtersT + (size_t)id1 * 8);
        float4 b1 = *(const float4*)(filtersT + (size_t)id1 * 8 + 4);
        float4 a2 = *(const float4*)(filtersT + (size_t)id2 * 8);
        float4 b2 = *(const float4*)(filtersT + (size_t)id2 * 8 + 4);
        float4 a3 = *(const float4*)(filtersT + (size_t)id3 * 8);
        float4 b3 = *(const float4*)(filtersT + (size_t)id3 * 8 + 4);
        acc[0] += v0 * a0.x + v1 * a1.x + v2 * a2.x + v3 * a3.x;
        acc[1] += v0 * a0.y + v1 * a1.y + v2 * a2.y + v3 * a3.y;
        acc[2] += v0 * a0.z + v1 * a1.z + v2 * a2.z + v3 * a3.z;
        acc[3] += v0 * a0.w + v1 * a1.w + v2 * a2.w + v3 * a3.w;
        acc[4] += v0 * b0.x + v1 * b1.x + v2 * b2.x + v3 * b3.x;
        acc[5] += v0 * b0.y + v1 * b1.y + v2 * b2.y + v3 * b3.y;
        acc[6] += v0 * b0.z + v1 * b1.z + v2 * b2.z + v3 * b3.z;
        acc[7] += v0 * b0.w + v1 * b1.w + v2 * b2.w + v3 * b3.w;
    }
    for (; i < e; i += 4) {
        int sid = snp_ids[i];
        float val = snpT[(size_t)sid * 16 + b];
        float4 fa = *(const float4*)(filtersT + (size_t)sid * 8);
        float4 fb = *(const float4*)(filtersT + (size_t)sid * 8 + 4);
        acc[0] += val * fa.x; acc[1] += val * fa.y; acc[2] += val * fa.z; acc[3] += val * fa.w;
        acc[4] += val * fb.x; acc[5] += val * fb.y; acc[6] += val * fb.z; acc[7] += val * fb.w;
    }
    #pragma unroll
    for (int f = 0; f < 8; f++) {
        acc[f] += __shfl_xor(acc[f], 16, 64);
        acc[f] += __shfl_xor(acc[f], 32, 64);
    }
    if (lane < 16) {   // lane == b
        float* dst = h_gm + (size_t)g * 128 + lane * 8;
        *(float4*)(dst)     = make_float4(acc[0], acc[1], acc[2], acc[3]);
        *(float4*)(dst + 4) = make_float4(acc[4], acc[5], acc[6], acc[7]);
    }
}

// ---------------------------------------------------------------------------
// GIN layer v3: 32 threads per gene (8 genes/block). Each thread owns one
// float4 of the 512B gene-major row. Edge loop unrolled x4 -> 4 independent
// coalesced float4 loads in flight. MLP via LDS roundtrip.
__global__ __launch_bounds__(256) void k_gin_v3(const float* __restrict__ hin,   // [g][128]
                                                float* __restrict__ hout,        // [g][128]
                                                const int* __restrict__ csr_off,
                                                const int* __restrict__ csr_src,
                                                const float* __restrict__ eps_l,
                                                const float* __restrict__ W1,
                                                const float* __restrict__ b1,
                                                const float* __restrict__ g1,
                                                const float* __restrict__ bt1,
                                                const float* __restrict__ W2,
                                                const float* __restrict__ b2,
                                                const float* __restrict__ g2,
                                                const float* __restrict__ bt2) {
    __shared__ float sW1[128], sb1[16], sg1[16], sbt1[16];
    __shared__ float sW2[128], sb2[8], sg2[8], sbt2[8];
    __shared__ float sZ[8][128];
    int t = threadIdx.x;
    if (t < 128) { sW1[t] = W1[t]; sW2[t] = W2[t]; }
    if (t < 16)  { sb1[t] = b1[t]; sg1[t] = g1[t]; sbt1[t] = bt1[t]; }
    if (t < 8)   { sb2[t] = b2[t]; sg2[t] = g2[t]; sbt2[t] = bt2[t]; }

    int lane32 = t & 31;
    int gidx = t >> 5;                       // 0..7
    int g = blockIdx.x * 8 + gidx;
    float epsv = 1.0f + eps_l[0];

    float4 acc = *(const float4*)(hin + (size_t)g * 128 + lane32 * 4);
    acc.x *= epsv; acc.y *= epsv; acc.z *= epsv; acc.w *= epsv;

    int s = csr_off[g], e = csr_off[g + 1];
    int k = s;
    for (; k + 3 < e; k += 4) {
        int s0 = csr_src[k];
        int s1 = csr_src[k + 1];
        int s2 = csr_src[k + 2];
        int s3 = csr_src[k + 3];
        float4 v0 = *(const float4*)(hin + (size_t)s0 * 128 + lane32 * 4);
        float4 v1 = *(const float4*)(hin + (size_t)s1 * 128 + lane32 * 4);
        float4 v2 = *(const float4*)(hin + (size_t)s2 * 128 + lane32 * 4);
        float4 v3 = *(const float4*)(hin + (size_t)s3 * 128 + lane32 * 4);
        acc.x += v0.x + v1.x + v2.x + v3.x;
        acc.y += v0.y + v1.y + v2.y + v3.y;
        acc.z += v0.z + v1.z + v2.z + v3.z;
        acc.w += v0.w + v1.w + v2.w + v3.w;
    }
    for (; k < e; k++) {
        int s0 = csr_src[k];
        float4 v0 = *(const float4*)(hin + (size_t)s0 * 128 + lane32 * 4);
        acc.x += v0.x; acc.y += v0.y; acc.z += v0.z; acc.w += v0.w;
    }
    *(float4*)(&sZ[gidx][lane32 * 4]) = acc;
    __syncthreads();

    if (t < 128) {
        int gs = t >> 4, b = t & 15;
        int gg = blockIdx.x * 8 + gs;
        float z[8];
        #pragma unroll
        for (int i = 0; i < 8; i++) z[i] = sZ[gs][b * 8 + i];
        float o[8];
        #pragma unroll
        for (int f = 0; f < 8; f++) o[f] = sb2[f];
        #pragma unroll
        for (int j = 0; j < 16; j++) {
            float s1 = sb1[j];
            #pragma unroll
            for (int i = 0; i < 8; i++) s1 += z[i] * sW1[i * 16 + j];
            s1 = s1 * BN_SCALE * sg1[j] + sbt1[j];
            s1 = gelu_erf(s1);
            #pragma unroll
            for (int f = 0; f < 8; f++) o[f] += s1 * sW2[j * 8 + f];
        }
        float r[8];
        #pragma unroll
        for (int f = 0; f < 8; f++) {
            float v = o[f] * BN_SCALE * sg2[f] + sbt2[f];
            r[f] = gelu_erf(v);
        }
        float* ho = hout + (size_t)gg * 128 + b * 8;
        *(float4*)(ho)     = make_float4(r[0], r[1], r[2], r[3]);
        *(float4*)(ho + 4) = make_float4(r[4], r[5], r[6], r[7]);
    }
    // remaining genes' MLP: second half of the 8 genes handled by t in [128,256)
    else {
        int gs = (t - 128) >> 4;              // 0..7 -> genes 4..7? no: see below
    }
}

// NOTE: the MLP above covers gs 0..7 via t<128? 128 threads = 8 genes x 16 b. Yes:
// gs = t>>4 in 0..7, b = t&15 — all 8 genes covered by t<128. The else branch is dead.

// ---------------------------------------------------------------------------
// Attentive readout, gene-major input. Block = 256 threads = 16 genes x 16 b.
__global__ __launch_bounds__(256) void k_readout_gm(const float* __restrict__ h,  // [g][128]
                                                    const float* __restrict__ Wk,
                                                    const float* __restrict__ bk,
                                                    const float* __restrict__ Wq,
                                                    const float* __restrict__ Wv,
                                                    const float* __restrict__ bv,
                                                    float* __restrict__ w_out,   // [b][g]
                                                    float* __restrict__ g_h) {
    __shared__ float sWk[64], sWv[64], sbk[8], sbv[8], sWq[8];
    __shared__ float sRed[4][16][8];
    __shared__ float sWout[16][17];          // [gene_sub][b], padded
    int t = threadIdx.x;
    if (t < 64) { sWk[t] = Wk[t]; sWv[t] = Wv[t]; }
    if (t < 8)  { sbk[t] = bk[t]; sbv[t] = bv[t]; sWq[t] = Wq[t]; }
    __syncthreads();

    int gs = t >> 4;                          // 0..15
    int b  = t & 15;
    int g  = blockIdx.x * 16 + gs;

    const float* hr = h + (size_t)g * 128 + b * 8;
    float hv[8];
    float4 h0 = *(const float4*)(hr);
    float4 h1 = *(const float4*)(hr + 4);
    hv[0]=h0.x; hv[1]=h0.y; hv[2]=h0.z; hv[3]=h0.w;
    hv[4]=h1.x; hv[5]=h1.y; hv[6]=h1.z; hv[7]=h1.w;

    float q = 0.0f;
    #pragma unroll
    for (int j = 0; j < 8; j++) {
        float key = sbk[j];
        #pragma unroll
        for (int i = 0; i < 8; i++) key += hv[i] * sWk[i * 8 + j];
        q += key * sWq[j];
    }
    float w = sigmoidf_(q);
    sWout[gs][b] = w;

    float contrib[8];
    #pragma unroll
    for (int f = 0; f < 8; f++) {
        float v = sbv[f];
        #pragma unroll
        for (int i = 0; i < 8; i++) v += hv[i] * sWv[i * 8 + f];
        contrib[f] = v * w;
    }
    // reduce over the 4 genes within this wave (lanes differ by 16, 32)
    #pragma unroll
    for (int f = 0; f < 8; f++) {
        contrib[f] += __shfl_xor(contrib[f], 16, 64);
        contrib[f] += __shfl_xor(contrib[f], 32, 64);
    }
    int wave = t >> 6, lane = t & 63;
    if (lane < 16) {
        #pragma unroll
        for (int f = 0; f < 8; f++) sRed[wave][lane][f] = contrib[f];
    }
    __syncthreads();
    if (t < 128) {
        int bb = t >> 3, f = t & 7;
        float s = sRed[0][bb][f] + sRed[1][bb][f] + sRed[2][bb][f] + sRed[3][bb][f];
        atomicAdd(&g_h[bb * 8 + f], s);
    }
    // coalesced w output: 16 consecutive genes per (b)
    {
        int bb = t >> 4, gi = t & 15;
        w_out[(size_t)bb * NGENES + blockIdx.x * 16 + gi] = sWout[gi][bb];
    }
}

// ---------------------------------------------------------------------------
__global__ __launch_bounds__(1024) void k_head(const float* __restrict__ g_h,
                                               const float* __restrict__ Wp1, const float* __restrict__ bp1,
                                               const float* __restrict__ gp1, const float* __restrict__ btp1,
                                               const float* __restrict__ Wp2, const float* __restrict__ bp2,
                                               const float* __restrict__ gp2, const float* __restrict__ btp2,
                                               const float* __restrict__ Wp3, const float* __restrict__ bp3,
                                               float* __restrict__ preds) {
    __shared__ float sgh[128];
    __shared__ float z1[16 * 64];
    __shared__ float z2[16 * 16];
    int t = threadIdx.x;
    if (t < 128) sgh[t] = g_h[t];
    __syncthreads();
    {
        int b = t >> 6, j = t & 63;
        float s = bp1[j];
        #pragma unroll
        for (int k = 0; k < 8; k++) s += sgh[b * 8 + k] * Wp1[k * 64 + j];
        s = s * BN_SCALE * gp1[j] + btp1[j];
        z1[b * 64 + j] = gelu_erf(s);
    }
    __syncthreads();
    if (t < 256) {
        int b = t >> 4, j = t & 15;
        float s = bp2[j];
        for (int k = 0; k < 64; k++) s += z1[b * 64 + k] * Wp2[k * 16 + j];
        s = s * BN_SCALE * gp2[j] + btp2[j];
        z2[b * 16 + j] = gelu_erf(s);
    }
    __syncthreads();
    if (t < 16) {
        float s = bp3[0];
        #pragma unroll
        for (int k = 0; k < 16; k++) s += z2[t * 16 + k] * Wp3[k];
        preds[t] = s;
    }
}

// ---------------------------------------------------------------------------
__global__ __launch_bounds__(256) void k_copy4(const float4* __restrict__ src,
                                               float4* __restrict__ dst, int n4) {
    int i = blockIdx.x * 256 + threadIdx.x;
    if (i < n4) dst[i] = src[i];
}

// ---------------------------------------------------------------------------
extern "C" void kernel_launch(void* const* d_in, const int* in_sizes, int n_in,
                              void* d_out, int out_size, void* d_ws, size_t ws_size,
                              hipStream_t stream) {
    const float* snp          = (const float*)d_in[0];
    const int*   snp_ids      = (const int*)  d_in[1];
    const int*   gene_of_node = (const int*)  d_in[2];
    const int*   edge_src     = (const int*)  d_in[3];
    const int*   edge_dst     = (const int*)  d_in[4];
    const float* filters      = (const float*)d_in[5];
    const float* eps          = (const float*)d_in[6];
    const float* W1  = (const float*)d_in[7];
    const float* b1  = (const float*)d_in[8];
    const float* g1  = (const float*)d_in[9];
    const float* bt1 = (const float*)d_in[10];
    const float* W2  = (const float*)d_in[11];
    const float* b2  = (const float*)d_in[12];
    const float* g2  = (const float*)d_in[13];
    const float* bt2 = (const float*)d_in[14];
    const float* Wk  = (const float*)d_in[15];
    const float* bk  = (const float*)d_in[16];
    const float* Wq  = (const float*)d_in[17];
    const float* Wv  = (const float*)d_in[18];
    const float* bv  = (const float*)d_in[19];
    const float* Wp1 = (const float*)d_in[20];
    const float* bp1 = (const float*)d_in[21];
    const float* gp1 = (const float*)d_in[22];
    const float* btp1= (const float*)d_in[23];
    const float* Wp2 = (const float*)d_in[24];
    const float* bp2 = (const float*)d_in[25];
    const float* gp2 = (const float*)d_in[26];
    const float* btp2= (const float*)d_in[27];
    const float* Wp3 = (const float*)d_in[28];
    const float* bp3 = (const float*)d_in[29];

    float* out        = (float*)d_out;
    float* out_preds  = out;
    float* out_filt   = out + 16;
    float* out_w      = out + 16 + NFILT * NSNPS;

    // filtersT scratch lives in the d_out filters region (16 MB), overwritten
    // by the real filters copy at the very end.
    float* filtersT = out_filt;

    // ---- workspace layout. snpT (32 MB) dead after snp2gene; h1_gm aliases it.
    char* ws = (char*)d_ws;
    size_t off = 0;
    float* h0_gm = (float*)(ws + off); off += (size_t)BB * NGENES * NFILT * 4;  // 10.24 MB
    float* snpT  = (float*)(ws + off);
    float* h1_gm = snpT;                                                        // alias (disjoint in time)
    off += (size_t)NSNPS * BB * 4;                                              // 32 MB
    int* node_off = (int*)(ws + off); off += ((NGENES + 1) * 4 + 255) / 256 * 256;
    int* deg      = (int*)(ws + off); off += (NGENES * 4 + 255) / 256 * 256;
    int* csr_off  = (int*)(ws + off); off += ((NGENES + 1) * 4 + 255) / 256 * 256;
    int* cursor   = (int*)(ws + off); off += (NGENES * 4 + 255) / 256 * 256;
    int* csr_src  = (int*)(ws + off); off += (size_t)NEDGES * 4;
    float* g_h    = (float*)(ws + off); off += 256;

    // 1. transposes
    k_transpose<<<(NFILT * NSNPS + 255) / 256, 256, 0, stream>>>(filters, filtersT);
    k_snpT<<<(NSNPS + 255) / 256, 256, 0, stream>>>(snp, snpT);
    // 2. gene node offsets
    k_node_off<<<(NGENES + 1 + 255) / 256, 256, 0, stream>>>(gene_of_node, node_off);
    // 3. CSR build
    k_zero<<<(NGENES + 255) / 256, 256, 0, stream>>>(deg, g_h);
    k_deg<<<(NEDGES + 255) / 256, 256, 0, stream>>>(edge_dst, deg);
    k_scan<<<1, 1024, 0, stream>>>(deg, csr_off, cursor);
    k_scatter<<<(NEDGES + 255) / 256, 256, 0, stream>>>(edge_src, edge_dst, cursor, csr_src);
    // 4. SNP -> gene readout (gene-major, unrolled x4)
    k_snp2gene_v4<<<NGENES / 4, 256, 0, stream>>>(snpT, snp_ids, node_off, filtersT, h0_gm);
    // 5. GIN layers (32 threads/gene, unrolled x4, gene-major in/out)
    k_gin_v3<<<NGENES / 8, 256, 0, stream>>>(h0_gm, h1_gm, csr_off, csr_src, eps + 0,
                                             W1 + 0 * 128, b1 + 0 * 16, g1 + 0 * 16, bt1 + 0 * 16,
                                             W2 + 0 * 128, b2 + 0 * 8, g2 + 0 * 8, bt2 + 0 * 8);
    k_gin_v3<<<NGENES / 8, 256, 0, stream>>>(h1_gm, h0_gm, csr_off, csr_src, eps + 1,
                                             W1 + 1 * 128, b1 + 1 * 16, g1 + 1 * 16, bt1 + 1 * 16,
                                             W2 + 1 * 128, b2 + 1 * 8, g2 + 1 * 8, bt2 + 1 * 8);
    // 6. attentive readout (gene-major input)
    k_readout_gm<<<NGENES / 16, 256, 0, stream>>>(h0_gm, Wk, bk, Wq, Wv, bv, out_w, g_h);
    // 7. head MLP
    k_head<<<1, 1024, 0, stream>>>(g_h, Wp1, bp1, gp1, btp1, Wp2, bp2, gp2, btp2, Wp3, bp3, out_preds);
    // 8. filters passthrough (overwrites filtersT scratch)
    k_copy4<<<(NFILT * NSNPS / 4 + 255) / 256, 256, 0, stream>>>((const float4*)filters,
                                                                 (float4*)out_filt,
                                                                 NFILT * NSNPS / 4);
}

// Round 5
// 394.611 us; speedup vs baseline: 1.3356x; 1.0879x over previous
//
#include <hip/hip_runtime.h>
#include <math.h>

#define NSNPS  500000
#define NGENES 20000
#define NNODES 600000
#define NEDGES 320000
#define BB     16
#define NFILT  8

// rsqrt(1 + 1e-5)
#define BN_SCALE 0.99999500003749968f

__device__ __forceinline__ float gelu_erf(float x) {
    return 0.5f * x * (1.0f + erff(x * 0.70710678118654752f));
}
__device__ __forceinline__ float sigmoidf_(float x) {
    return 1.0f / (1.0f + expf(-x));
}

// ---------------------------------------------------------------------------
// filters [NFILT, NSNPS] -> filtersT [NSNPS, NFILT]
__global__ __launch_bounds__(256) void k_transpose(const float* __restrict__ filters,
                                                   float* __restrict__ filtersT) {
    int idx = blockIdx.x * 256 + threadIdx.x;
    if (idx >= NFILT * NSNPS) return;
    int f = idx / NSNPS;
    int n = idx - f * NSNPS;
    filtersT[n * NFILT + f] = filters[idx];
}

// ---------------------------------------------------------------------------
// snp [BB, NSNPS] -> snpT [NSNPS, BB]
__global__ __launch_bounds__(256) void k_snpT(const float* __restrict__ snp,
                                              float* __restrict__ snpT) {
    int n = blockIdx.x * 256 + threadIdx.x;
    if (n >= NSNPS) return;
    float v[16];
    #pragma unroll
    for (int b = 0; b < 16; b++) v[b] = snp[(size_t)b * NSNPS + n];
    float4* dst = (float4*)(snpT + (size_t)n * 16);
    dst[0] = make_float4(v[0], v[1], v[2], v[3]);
    dst[1] = make_float4(v[4], v[5], v[6], v[7]);
    dst[2] = make_float4(v[8], v[9], v[10], v[11]);
    dst[3] = make_float4(v[12], v[13], v[14], v[15]);
}

// ---------------------------------------------------------------------------
// node_off[g] = lower_bound(gene_of_node, g); also zeros deg and g_h.
__global__ __launch_bounds__(256) void k_node_off(const int* __restrict__ gene_of_node,
                                                  int* __restrict__ node_off,
                                                  int* __restrict__ deg,
                                                  float* __restrict__ g_h) {
    int g = blockIdx.x * 256 + threadIdx.x;
    if (g < NGENES) deg[g] = 0;
    if (g < BB * NFILT) g_h[g] = 0.0f;
    if (g > NGENES) return;
    int lo = 0, hi = NNODES;
    while (lo < hi) {
        int mid = (lo + hi) >> 1;
        if (gene_of_node[mid] < g) lo = mid + 1; else hi = mid;
    }
    node_off[g] = lo;
}

// ---------------------------------------------------------------------------
__global__ __launch_bounds__(256) void k_deg(const int* __restrict__ edge_dst,
                                             int* __restrict__ deg) {
    int e = blockIdx.x * 256 + threadIdx.x;
    if (e >= NEDGES) return;
    atomicAdd(&deg[edge_dst[e]], 1);
}

__global__ __launch_bounds__(1024) void k_scan(const int* __restrict__ deg,
                                               int* __restrict__ csr_off,
                                               int* __restrict__ cursor) {
    __shared__ int sums[1024];
    int t = threadIdx.x;
    const int CH = (NGENES + 1023) / 1024;   // 20
    int base = t * CH;
    int s = 0;
    for (int i = 0; i < CH; i++) {
        int idx = base + i;
        if (idx < NGENES) s += deg[idx];
    }
    sums[t] = s;
    __syncthreads();
    for (int off = 1; off < 1024; off <<= 1) {
        int v = (t >= off) ? sums[t - off] : 0;
        __syncthreads();
        sums[t] += v;
        __syncthreads();
    }
    int run = (t == 0) ? 0 : sums[t - 1];
    for (int i = 0; i < CH; i++) {
        int idx = base + i;
        if (idx < NGENES) {
            csr_off[idx] = run;
            cursor[idx]  = run;
            run += deg[idx];
        }
    }
    if (t == 1023) csr_off[NGENES] = sums[1023];
}

__global__ __launch_bounds__(256) void k_scatter(const int* __restrict__ edge_src,
                                                 const int* __restrict__ edge_dst,
                                                 int* __restrict__ cursor,
                                                 int* __restrict__ csr_src) {
    int e = blockIdx.x * 256 + threadIdx.x;
    if (e >= NEDGES) return;
    int p = atomicAdd(&cursor[edge_dst[e]], 1);
    csr_src[p] = edge_src[e];
}

// ---------------------------------------------------------------------------
// v5: TWO waves per gene (node halves), 2 genes per block. lane = sub4*16 + b,
// global sub = pair*4 + sub4 in [0,8), stride 8. Unroll x4 + x2 remainder.
// Cross-wave combine via LDS; coalesced 1KB/block gene-major store.
__global__ __launch_bounds__(256) void k_snp2gene_v5(const float* __restrict__ snpT,
                                                     const int* __restrict__ snp_ids,
                                                     const int* __restrict__ node_off,
                                                     const float* __restrict__ filtersT,
                                                     float* __restrict__ h_gm) {
    __shared__ float sZ[2][2][128];
    int t = threadIdx.x;
    int waveIdx = t >> 6, lane = t & 63;
    int gidx = waveIdx >> 1;                 // 0..1
    int pair = waveIdx & 1;                  // node half
    int g = blockIdx.x * 2 + gidx;
    int sub = (pair << 2) + (lane >> 4);     // 0..7
    int b = lane & 15;
    int s = node_off[g], e = node_off[g + 1];

    float acc[8];
    #pragma unroll
    for (int f = 0; f < 8; f++) acc[f] = 0.0f;

    int i = s + sub;
    for (; i + 24 < e; i += 32) {
        int id0 = snp_ids[i];
        int id1 = snp_ids[i + 8];
        int id2 = snp_ids[i + 16];
        int id3 = snp_ids[i + 24];
        float v0 = snpT[(size_t)id0 * 16 + b];
        float v1 = snpT[(size_t)id1 * 16 + b];
        float v2 = snpT[(size_t)id2 * 16 + b];
        float v3 = snpT[(size_t)id3 * 16 + b];
        float4 a0 = *(const float4*)(filtersT + (size_t)id0 * 8);
        float4 c0 = *(const float4*)(filtersT + (size_t)id0 * 8 + 4);
        float4 a1 = *(const float4*)(filtersT + (size_t)id1 * 8);
        float4 c1 = *(const float4*)(filtersT + (size_t)id1 * 8 + 4);
        float4 a2 = *(const float4*)(filtersT + (size_t)id2 * 8);
        float4 c2 = *(const float4*)(filtersT + (size_t)id2 * 8 + 4);
        float4 a3 = *(const float4*)(filtersT + (size_t)id3 * 8);
        float4 c3 = *(const float4*)(filtersT + (size_t)id3 * 8 + 4);
        acc[0] += v0 * a0.x + v1 * a1.x + v2 * a2.x + v3 * a3.x;
        acc[1] += v0 * a0.y + v1 * a1.y + v2 * a2.y + v3 * a3.y;
        acc[2] += v0 * a0.z + v1 * a1.z + v2 * a2.z + v3 * a3.z;
        acc[3] += v0 * a0.w + v1 * a1.w + v2 * a2.w + v3 * a3.w;
        acc[4] += v0 * c0.x + v1 * c1.x + v2 * c2.x + v3 * c3.x;
        acc[5] += v0 * c0.y + v1 * c1.y + v2 * c2.y + v3 * c3.y;
        acc[6] += v0 * c0.z + v1 * c1.z + v2 * c2.z + v3 * c3.z;
        acc[7] += v0 * c0.w + v1 * c1.w + v2 * c2.w + v3 * c3.w;
    }
    for (; i + 8 < e; i += 16) {
        int id0 = snp_ids[i];
        int id1 = snp_ids[i + 8];
        float v0 = snpT[(size_t)id0 * 16 + b];
        float v1 = snpT[(size_t)id1 * 16 + b];
        float4 a0 = *(const float4*)(filtersT + (size_t)id0 * 8);
        float4 c0 = *(const float4*)(filtersT + (size_t)id0 * 8 + 4);
        float4 a1 = *(const float4*)(filtersT + (size_t)id1 * 8);
        float4 c1 = *(const float4*)(filtersT + (size_t)id1 * 8 + 4);
        acc[0] += v0 * a0.x + v1 * a1.x;
        acc[1] += v0 * a0.y + v1 * a1.y;
        acc[2] += v0 * a0.z + v1 * a1.z;
        acc[3] += v0 * a0.w + v1 * a1.w;
        acc[4] += v0 * c0.x + v1 * c1.x;
        acc[5] += v0 * c0.y + v1 * c1.y;
        acc[6] += v0 * c0.z + v1 * c1.z;
        acc[7] += v0 * c0.w + v1 * c1.w;
    }
    if (i < e) {
        int sid = snp_ids[i];
        float val = snpT[(size_t)sid * 16 + b];
        float4 fa = *(const float4*)(filtersT + (size_t)sid * 8);
        float4 fb = *(const float4*)(filtersT + (size_t)sid * 8 + 4);
        acc[0] += val * fa.x; acc[1] += val * fa.y; acc[2] += val * fa.z; acc[3] += val * fa.w;
        acc[4] += val * fb.x; acc[5] += val * fb.y; acc[6] += val * fb.z; acc[7] += val * fb.w;
    }
    #pragma unroll
    for (int f = 0; f < 8; f++) {
        acc[f] += __shfl_xor(acc[f], 16, 64);
        acc[f] += __shfl_xor(acc[f], 32, 64);
    }
    if (lane < 16) {   // lane == b
        float* dst = &sZ[gidx][pair][lane * 8];
        *(float4*)(dst)     = make_float4(acc[0], acc[1], acc[2], acc[3]);
        *(float4*)(dst + 4) = make_float4(acc[4], acc[5], acc[6], acc[7]);
    }
    __syncthreads();
    {
        int gg = blockIdx.x * 2 + (t >> 7);
        int c = t & 127;
        h_gm[(size_t)gg * 128 + c] = sZ[t >> 7][0][c] + sZ[t >> 7][1][c];
    }
}

// ---------------------------------------------------------------------------
// GIN aggregation, column-chunked for L2 residency. chunk = blockIdx & 3 so
// (with blockIdx%8 -> XCD) each XCD's L2 sees only a 2.56 MB column slice.
// Block = 32 genes x 8 threads; each thread owns one float4 of its chunk.
// Edge loop unrolled x8; no LDS, no barrier.
__global__ __launch_bounds__(256) void k_agg(const float* __restrict__ hin,   // [g][128]
                                             float* __restrict__ z,           // [g][128]
                                             const int* __restrict__ csr_off,
                                             const int* __restrict__ csr_src,
                                             const float* __restrict__ eps_l) {
    int t = threadIdx.x;
    int chunk = blockIdx.x & 3;
    int ggrp  = blockIdx.x >> 2;
    int g = ggrp * 32 + (t >> 3);
    int col = chunk * 32 + (t & 7) * 4;
    const float* __restrict__ hc = hin + col;
    float epsv = 1.0f + eps_l[0];

    float4 acc = *(const float4*)(hc + (size_t)g * 128);
    acc.x *= epsv; acc.y *= epsv; acc.z *= epsv; acc.w *= epsv;

    int s = csr_off[g], e = csr_off[g + 1];
    int k = s;
    for (; k + 7 < e; k += 8) {
        int i0 = csr_src[k];
        int i1 = csr_src[k + 1];
        int i2 = csr_src[k + 2];
        int i3 = csr_src[k + 3];
        int i4 = csr_src[k + 4];
        int i5 = csr_src[k + 5];
        int i6 = csr_src[k + 6];
        int i7 = csr_src[k + 7];
        float4 v0 = *(const float4*)(hc + (size_t)i0 * 128);
        float4 v1 = *(const float4*)(hc + (size_t)i1 * 128);
        float4 v2 = *(const float4*)(hc + (size_t)i2 * 128);
        float4 v3 = *(const float4*)(hc + (size_t)i3 * 128);
        float4 v4 = *(const float4*)(hc + (size_t)i4 * 128);
        float4 v5 = *(const float4*)(hc + (size_t)i5 * 128);
        float4 v6 = *(const float4*)(hc + (size_t)i6 * 128);
        float4 v7 = *(const float4*)(hc + (size_t)i7 * 128);
        acc.x += ((v0.x + v1.x) + (v2.x + v3.x)) + ((v4.x + v5.x) + (v6.x + v7.x));
        acc.y += ((v0.y + v1.y) + (v2.y + v3.y)) + ((v4.y + v5.y) + (v6.y + v7.y));
        acc.z += ((v0.z + v1.z) + (v2.z + v3.z)) + ((v4.z + v5.z) + (v6.z + v7.z));
        acc.w += ((v0.w + v1.w) + (v2.w + v3.w)) + ((v4.w + v5.w) + (v6.w + v7.w));
    }
    for (; k + 1 < e; k += 2) {
        int i0 = csr_src[k];
        int i1 = csr_src[k + 1];
        float4 v0 = *(const float4*)(hc + (size_t)i0 * 128);
        float4 v1 = *(const float4*)(hc + (size_t)i1 * 128);
        acc.x += v0.x + v1.x; acc.y += v0.y + v1.y;
        acc.z += v0.z + v1.z; acc.w += v0.w + v1.w;
    }
    if (k < e) {
        int i0 = csr_src[k];
        float4 v0 = *(const float4*)(hc + (size_t)i0 * 128);
        acc.x += v0.x; acc.y += v0.y; acc.z += v0.z; acc.w += v0.w;
    }
    *(float4*)(z + (size_t)g * 128 + col) = acc;
}

// ---------------------------------------------------------------------------
// GIN MLP over 320k rows (gene-major layout: row r = g*16+b).
__global__ __launch_bounds__(256) void k_mlp(const float* __restrict__ z,
                                             float* __restrict__ hout,
                                             const float* __restrict__ W1,
                                             const float* __restrict__ b1,
                                             const float* __restrict__ g1,
                                             const float* __restrict__ bt1,
                                             const float* __restrict__ W2,
                                             const float* __restrict__ b2,
                                             const float* __restrict__ g2,
                                             const float* __restrict__ bt2) {
    __shared__ float sW1[128], sb1[16], sg1[16], sbt1[16];
    __shared__ float sW2[128], sb2[8], sg2[8], sbt2[8];
    int t = threadIdx.x;
    if (t < 128) { sW1[t] = W1[t]; sW2[t] = W2[t]; }
    if (t < 16)  { sb1[t] = b1[t]; sg1[t] = g1[t]; sbt1[t] = bt1[t]; }
    if (t < 8)   { sb2[t] = b2[t]; sg2[t] = g2[t]; sbt2[t] = bt2[t]; }
    __syncthreads();

    size_t r = (size_t)blockIdx.x * 256 + t;     // 0 .. 320000
    float4 za = *(const float4*)(z + r * 8);
    float4 zb = *(const float4*)(z + r * 8 + 4);
    float zz[8] = { za.x, za.y, za.z, za.w, zb.x, zb.y, zb.z, zb.w };

    float o[8];
    #pragma unroll
    for (int f = 0; f < 8; f++) o[f] = sb2[f];
    #pragma unroll
    for (int j = 0; j < 16; j++) {
        float s1 = sb1[j];
        #pragma unroll
        for (int i = 0; i < 8; i++) s1 += zz[i] * sW1[i * 16 + j];
        s1 = s1 * BN_SCALE * sg1[j] + sbt1[j];
        s1 = gelu_erf(s1);
        #pragma unroll
        for (int f = 0; f < 8; f++) o[f] += s1 * sW2[j * 8 + f];
    }
    float rr[8];
    #pragma unroll
    for (int f = 0; f < 8; f++) {
        float v = o[f] * BN_SCALE * sg2[f] + sbt2[f];
        rr[f] = gelu_erf(v);
    }
    *(float4*)(hout + r * 8)     = make_float4(rr[0], rr[1], rr[2], rr[3]);
    *(float4*)(hout + r * 8 + 4) = make_float4(rr[4], rr[5], rr[6], rr[7]);
}

// ---------------------------------------------------------------------------
// Attentive readout, gene-major input. Block = 256 threads = 16 genes x 16 b.
__global__ __launch_bounds__(256) void k_readout_gm(const float* __restrict__ h,  // [g][128]
                                                    const float* __restrict__ Wk,
                                                    const float* __restrict__ bk,
                                                    const float* __restrict__ Wq,
                                                    const float* __restrict__ Wv,
                                                    const float* __restrict__ bv,
                                                    float* __restrict__ w_out,   // [b][g]
                                                    float* __restrict__ g_h) {
    __shared__ float sWk[64], sWv[64], sbk[8], sbv[8], sWq[8];
    __shared__ float sRed[4][16][8];
    __shared__ float sWout[16][17];          // [gene_sub][b], padded
    int t = threadIdx.x;
    if (t < 64) { sWk[t] = Wk[t]; sWv[t] = Wv[t]; }
    if (t < 8)  { sbk[t] = bk[t]; sbv[t] = bv[t]; sWq[t] = Wq[t]; }
    __syncthreads();

    int gs = t >> 4;                          // 0..15
    int b  = t & 15;
    int g  = blockIdx.x * 16 + gs;

    const float* hr = h + (size_t)g * 128 + b * 8;
    float hv[8];
    float4 h0 = *(const float4*)(hr);
    float4 h1 = *(const float4*)(hr + 4);
    hv[0]=h0.x; hv[1]=h0.y; hv[2]=h0.z; hv[3]=h0.w;
    hv[4]=h1.x; hv[5]=h1.y; hv[6]=h1.z; hv[7]=h1.w;

    float q = 0.0f;
    #pragma unroll
    for (int j = 0; j < 8; j++) {
        float key = sbk[j];
        #pragma unroll
        for (int i = 0; i < 8; i++) key += hv[i] * sWk[i * 8 + j];
        q += key * sWq[j];
    }
    float w = sigmoidf_(q);
    sWout[gs][b] = w;

    float contrib[8];
    #pragma unroll
    for (int f = 0; f < 8; f++) {
        float v = sbv[f];
        #pragma unroll
        for (int i = 0; i < 8; i++) v += hv[i] * sWv[i * 8 + f];
        contrib[f] = v * w;
    }
    #pragma unroll
    for (int f = 0; f < 8; f++) {
        contrib[f] += __shfl_xor(contrib[f], 16, 64);
        contrib[f] += __shfl_xor(contrib[f], 32, 64);
    }
    int wave = t >> 6, lane = t & 63;
    if (lane < 16) {
        #pragma unroll
        for (int f = 0; f < 8; f++) sRed[wave][lane][f] = contrib[f];
    }
    __syncthreads();
    if (t < 128) {
        int bb = t >> 3, f = t & 7;
        float s = sRed[0][bb][f] + sRed[1][bb][f] + sRed[2][bb][f] + sRed[3][bb][f];
        atomicAdd(&g_h[bb * 8 + f], s);
    }
    {
        int bb = t >> 4, gi = t & 15;
        w_out[(size_t)bb * NGENES + blockIdx.x * 16 + gi] = sWout[gi][bb];
    }
}

// ---------------------------------------------------------------------------
__global__ __launch_bounds__(1024) void k_head(const float* __restrict__ g_h,
                                               const float* __restrict__ Wp1, const float* __restrict__ bp1,
                                               const float* __restrict__ gp1, const float* __restrict__ btp1,
                                               const float* __restrict__ Wp2, const float* __restrict__ bp2,
                                               const float* __restrict__ gp2, const float* __restrict__ btp2,
                                               const float* __restrict__ Wp3, const float* __restrict__ bp3,
                                               float* __restrict__ preds) {
    __shared__ float sgh[128];
    __shared__ float z1[16 * 64];
    __shared__ float z2[16 * 16];
    int t = threadIdx.x;
    if (t < 128) sgh[t] = g_h[t];
    __syncthreads();
    {
        int b = t >> 6, j = t & 63;
        float s = bp1[j];
        #pragma unroll
        for (int k = 0; k < 8; k++) s += sgh[b * 8 + k] * Wp1[k * 64 + j];
        s = s * BN_SCALE * gp1[j] + btp1[j];
        z1[b * 64 + j] = gelu_erf(s);
    }
    __syncthreads();
    if (t < 256) {
        int b = t >> 4, j = t & 15;
        float s = bp2[j];
        for (int k = 0; k < 64; k++) s += z1[b * 64 + k] * Wp2[k * 16 + j];
        s = s * BN_SCALE * gp2[j] + btp2[j];
        z2[b * 16 + j] = gelu_erf(s);
    }
    __syncthreads();
    if (t < 16) {
        float s = bp3[0];
        #pragma unroll
        for (int k = 0; k < 16; k++) s += z2[t * 16 + k] * Wp3[k];
        preds[t] = s;
    }
}

// ---------------------------------------------------------------------------
__global__ __launch_bounds__(256) void k_copy4(const float4* __restrict__ src,
                                               float4* __restrict__ dst, int n4) {
    int i = blockIdx.x * 256 + threadIdx.x;
    if (i < n4) dst[i] = src[i];
}

// ---------------------------------------------------------------------------
extern "C" void kernel_launch(void* const* d_in, const int* in_sizes, int n_in,
                              void* d_out, int out_size, void* d_ws, size_t ws_size,
                              hipStream_t stream) {
    const float* snp          = (const float*)d_in[0];
    const int*   snp_ids      = (const int*)  d_in[1];
    const int*   gene_of_node = (const int*)  d_in[2];
    const int*   edge_src     = (const int*)  d_in[3];
    const int*   edge_dst     = (const int*)  d_in[4];
    const float* filters      = (const float*)d_in[5];
    const float* eps          = (const float*)d_in[6];
    const float* W1  = (const float*)d_in[7];
    const float* b1  = (const float*)d_in[8];
    const float* g1  = (const float*)d_in[9];
    const float* bt1 = (const float*)d_in[10];
    const float* W2  = (const float*)d_in[11];
    const float* b2  = (const float*)d_in[12];
    const float* g2  = (const float*)d_in[13];
    const float* bt2 = (const float*)d_in[14];
    const float* Wk  = (const float*)d_in[15];
    const float* bk  = (const float*)d_in[16];
    const float* Wq  = (const float*)d_in[17];
    const float* Wv  = (const float*)d_in[18];
    const float* bv  = (const float*)d_in[19];
    const float* Wp1 = (const float*)d_in[20];
    const float* bp1 = (const float*)d_in[21];
    const float* gp1 = (const float*)d_in[22];
    const float* btp1= (const float*)d_in[23];
    const float* Wp2 = (const float*)d_in[24];
    const float* bp2 = (const float*)d_in[25];
    const float* gp2 = (const float*)d_in[26];
    const float* btp2= (const float*)d_in[27];
    const float* Wp3 = (const float*)d_in[28];
    const float* bp3 = (const float*)d_in[29];

    float* out        = (float*)d_out;
    float* out_preds  = out;
    float* out_filt   = out + 16;
    float* out_w      = out + 16 + NFILT * NSNPS;

    // filtersT scratch lives in the d_out filters region (16 MB), overwritten
    // by the real filters copy at the very end.
    float* filtersT = out_filt;

    // ---- workspace layout. snpT (32 MB) dead after snp2gene; h1 and z alias
    // disjoint parts of it.
    char* ws = (char*)d_ws;
    size_t off = 0;
    float* h0   = (float*)(ws + off); off += (size_t)BB * NGENES * NFILT * 4;   // 10.24 MB
    float* snpT = (float*)(ws + off);
    float* h1   = snpT;                                                         // alias (after snp2gene)
    float* z    = snpT + (size_t)BB * NGENES * NFILT;                           // alias, next 10.24 MB
    off += (size_t)NSNPS * BB * 4;                                              // 32 MB
    int* node_off = (int*)(ws + off); off += ((NGENES + 1) * 4 + 255) / 256 * 256;
    int* deg      = (int*)(ws + off); off += (NGENES * 4 + 255) / 256 * 256;
    int* csr_off  = (int*)(ws + off); off += ((NGENES + 1) * 4 + 255) / 256 * 256;
    int* cursor   = (int*)(ws + off); off += (NGENES * 4 + 255) / 256 * 256;
    int* csr_src  = (int*)(ws + off); off += (size_t)NEDGES * 4;
    float* g_h    = (float*)(ws + off); off += 256;

    // 1. transposes
    k_transpose<<<(NFILT * NSNPS + 255) / 256, 256, 0, stream>>>(filters, filtersT);
    k_snpT<<<(NSNPS + 255) / 256, 256, 0, stream>>>(snp, snpT);
    // 2. gene node offsets (+ zero deg, g_h)
    k_node_off<<<(NGENES + 1 + 255) / 256, 256, 0, stream>>>(gene_of_node, node_off, deg, g_h);
    // 3. CSR build
    k_deg<<<(NEDGES + 255) / 256, 256, 0, stream>>>(edge_dst, deg);
    k_scan<<<1, 1024, 0, stream>>>(deg, csr_off, cursor);
    k_scatter<<<(NEDGES + 255) / 256, 256, 0, stream>>>(edge_src, edge_dst, cursor, csr_src);
    // 4. SNP -> gene readout (2 waves/gene, gene-major output)
    k_snp2gene_v5<<<NGENES / 2, 256, 0, stream>>>(snpT, snp_ids, node_off, filtersT, h0);
    // 5. GIN layers: agg (L2-chunked) + mlp (streaming)
    k_agg<<<(NGENES / 32) * 4, 256, 0, stream>>>(h0, z, csr_off, csr_src, eps + 0);
    k_mlp<<<NGENES * BB / 256, 256, 0, stream>>>(z, h1,
                                                 W1 + 0 * 128, b1 + 0 * 16, g1 + 0 * 16, bt1 + 0 * 16,
                                                 W2 + 0 * 128, b2 + 0 * 8, g2 + 0 * 8, bt2 + 0 * 8);
    k_agg<<<(NGENES / 32) * 4, 256, 0, stream>>>(h1, z, csr_off, csr_src, eps + 1);
    k_mlp<<<NGENES * BB / 256, 256, 0, stream>>>(z, h0,
                                                 W1 + 1 * 128, b1 + 1 * 16, g1 + 1 * 16, bt1 + 1 * 16,
                                                 W2 + 1 * 128, b2 + 1 * 8, g2 + 1 * 8, bt2 + 1 * 8);
    // 6. attentive readout (gene-major input)
    k_readout_gm<<<NGENES / 16, 256, 0, stream>>>(h0, Wk, bk, Wq, Wv, bv, out_w, g_h);
    // 7. head MLP
    k_head<<<1, 1024, 0, stream>>>(g_h, Wp1, bp1, gp1, btp1, Wp2, bp2, gp2, btp2, Wp3, bp3, out_preds);
    // 8. filters passthrough (overwrites filtersT scratch)
    k_copy4<<<(NFILT * NSNPS / 4 + 255) / 256, 256, 0, stream>>>((const float4*)filters,
                                                                 (float4*)out_filt,
                                                                 NFILT * NSNPS / 4);
}

// Round 6
// 356.887 us; speedup vs baseline: 1.4768x; 1.1057x over previous
//
#include <hip/hip_runtime.h>
#include <math.h>

#define NSNPS  500000
#define NGENES 20000
#define NNODES 600000
#define NEDGES 320000
#define BB     16
#define NFILT  8

// rsqrt(1 + 1e-5)
#define BN_SCALE 0.99999500003749968f

typedef unsigned short u16;

__device__ __forceinline__ float gelu_erf(float x) {
    return 0.5f * x * (1.0f + erff(x * 0.70710678118654752f));
}
__device__ __forceinline__ float sigmoidf_(float x) {
    return 1.0f / (1.0f + expf(-x));
}
// fp32 -> bf16 round-to-nearest-even
__device__ __forceinline__ u16 f2bf(float x) {
    unsigned u = __float_as_uint(x);
    u += 0x7fffu + ((u >> 16) & 1u);
    return (u16)(u >> 16);
}
__device__ __forceinline__ float bf1(u16 v)      { return __uint_as_float(((unsigned)v) << 16); }
__device__ __forceinline__ float bflo(unsigned v){ return __uint_as_float(v << 16); }
__device__ __forceinline__ float bfhi(unsigned v){ return __uint_as_float(v & 0xffff0000u); }
__device__ __forceinline__ unsigned pack2(float a, float b) {
    return (unsigned)f2bf(a) | ((unsigned)f2bf(b) << 16);
}

// ---------------------------------------------------------------------------
// Fused prep: [A] filtersT bf16, [B] snpT bf16, [C] node_off + zero deg/g_h,
// [E] filters fp32 passthrough copy. Sections are mutually independent.
#define PREP_NA 1954   // ceil(NSNPS/256)  filtersT
#define PREP_NB 1954   // snpT
#define PREP_NC 79     // ceil((NGENES+1)/256)
#define PREP_NE 3907   // ceil(NFILT*NSNPS/4/256) float4 copy
__global__ __launch_bounds__(256) void k_prep(const float* __restrict__ snp,
                                              const float* __restrict__ filters,
                                              const int* __restrict__ gene_of_node,
                                              u16* __restrict__ snpT,
                                              u16* __restrict__ filtT,
                                              float4* __restrict__ out_filt4,
                                              int* __restrict__ node_off,
                                              int* __restrict__ deg,
                                              float* __restrict__ g_h) {
    int bid = blockIdx.x;
    int t = threadIdx.x;
    if (bid < PREP_NA) {
        int n = bid * 256 + t;
        if (n < NSNPS) {
            uint4 p;
            p.x = pack2(filters[0 * NSNPS + n], filters[1 * NSNPS + n]);
            p.y = pack2(filters[2 * NSNPS + n], filters[3 * NSNPS + n]);
            p.z = pack2(filters[4 * NSNPS + n], filters[5 * NSNPS + n]);
            p.w = pack2(filters[6 * NSNPS + n], filters[7 * NSNPS + n]);
            *(uint4*)(filtT + (size_t)n * 8) = p;
        }
    } else if (bid < PREP_NA + PREP_NB) {
        int n = (bid - PREP_NA) * 256 + t;
        if (n < NSNPS) {
            uint4 p0, p1;
            p0.x = pack2(snp[0 * (size_t)NSNPS + n],  snp[1 * (size_t)NSNPS + n]);
            p0.y = pack2(snp[2 * (size_t)NSNPS + n],  snp[3 * (size_t)NSNPS + n]);
            p0.z = pack2(snp[4 * (size_t)NSNPS + n],  snp[5 * (size_t)NSNPS + n]);
            p0.w = pack2(snp[6 * (size_t)NSNPS + n],  snp[7 * (size_t)NSNPS + n]);
            p1.x = pack2(snp[8 * (size_t)NSNPS + n],  snp[9 * (size_t)NSNPS + n]);
            p1.y = pack2(snp[10 * (size_t)NSNPS + n], snp[11 * (size_t)NSNPS + n]);
            p1.z = pack2(snp[12 * (size_t)NSNPS + n], snp[13 * (size_t)NSNPS + n]);
            p1.w = pack2(snp[14 * (size_t)NSNPS + n], snp[15 * (size_t)NSNPS + n]);
            uint4* dst = (uint4*)(snpT + (size_t)n * 16);
            dst[0] = p0; dst[1] = p1;
        }
    } else if (bid < PREP_NA + PREP_NB + PREP_NC) {
        int g = (bid - PREP_NA - PREP_NB) * 256 + t;
        if (g < NGENES) deg[g] = 0;
        if (g < BB * NFILT) g_h[g] = 0.0f;
        if (g <= NGENES) {
            int lo = 0, hi = NNODES;
            while (lo < hi) {
                int mid = (lo + hi) >> 1;
                if (gene_of_node[mid] < g) lo = mid + 1; else hi = mid;
            }
            node_off[g] = lo;
        }
    } else {
        int i = (bid - PREP_NA - PREP_NB - PREP_NC) * 256 + t;
        if (i < NFILT * NSNPS / 4) out_filt4[i] = ((const float4*)filters)[i];
    }
}

// ---------------------------------------------------------------------------
__global__ __launch_bounds__(256) void k_deg(const int* __restrict__ edge_dst,
                                             int* __restrict__ deg) {
    int e = blockIdx.x * 256 + threadIdx.x;
    if (e >= NEDGES) return;
    atomicAdd(&deg[edge_dst[e]], 1);
}

__global__ __launch_bounds__(1024) void k_scan(const int* __restrict__ deg,
                                               int* __restrict__ csr_off,
                                               int* __restrict__ cursor) {
    __shared__ int sums[1024];
    int t = threadIdx.x;
    const int CH = (NGENES + 1023) / 1024;   // 20
    int base = t * CH;
    int s = 0;
    for (int i = 0; i < CH; i++) {
        int idx = base + i;
        if (idx < NGENES) s += deg[idx];
    }
    sums[t] = s;
    __syncthreads();
    for (int off = 1; off < 1024; off <<= 1) {
        int v = (t >= off) ? sums[t - off] : 0;
        __syncthreads();
        sums[t] += v;
        __syncthreads();
    }
    int run = (t == 0) ? 0 : sums[t - 1];
    for (int i = 0; i < CH; i++) {
        int idx = base + i;
        if (idx < NGENES) {
            csr_off[idx] = run;
            cursor[idx]  = run;
            run += deg[idx];
        }
    }
    if (t == 1023) csr_off[NGENES] = sums[1023];
}

__global__ __launch_bounds__(256) void k_scatter(const int* __restrict__ edge_src,
                                                 const int* __restrict__ edge_dst,
                                                 int* __restrict__ cursor,
                                                 int* __restrict__ csr_src) {
    int e = blockIdx.x * 256 + threadIdx.x;
    if (e >= NEDGES) return;
    int p = atomicAdd(&cursor[edge_dst[e]], 1);
    csr_src[p] = edge_src[e];
}

// ---------------------------------------------------------------------------
// v6 (bf16): TWO waves per gene, 2 genes per block. lane = sub4*16 + b.
// Per node: 2B snpT load + 16B filtersT load. fp32 accumulate, bf16 output.
__global__ __launch_bounds__(256) void k_snp2gene(const u16* __restrict__ snpT,
                                                  const int* __restrict__ snp_ids,
                                                  const int* __restrict__ node_off,
                                                  const u16* __restrict__ filtT,
                                                  u16* __restrict__ h_bf) {
    __shared__ float sZ[2][2][128];
    int t = threadIdx.x;
    int waveIdx = t >> 6, lane = t & 63;
    int gidx = waveIdx >> 1;
    int pair = waveIdx & 1;
    int g = blockIdx.x * 2 + gidx;
    int sub = (pair << 2) + (lane >> 4);     // 0..7
    int b = lane & 15;
    int s = node_off[g], e = node_off[g + 1];

    float acc[8];
    #pragma unroll
    for (int f = 0; f < 8; f++) acc[f] = 0.0f;

    int i = s + sub;
    for (; i + 24 < e; i += 32) {
        int id0 = snp_ids[i];
        int id1 = snp_ids[i + 8];
        int id2 = snp_ids[i + 16];
        int id3 = snp_ids[i + 24];
        float v0 = bf1(snpT[(size_t)id0 * 16 + b]);
        float v1 = bf1(snpT[(size_t)id1 * 16 + b]);
        float v2 = bf1(snpT[(size_t)id2 * 16 + b]);
        float v3 = bf1(snpT[(size_t)id3 * 16 + b]);
        uint4 F0 = *(const uint4*)(filtT + (size_t)id0 * 8);
        uint4 F1 = *(const uint4*)(filtT + (size_t)id1 * 8);
        uint4 F2 = *(const uint4*)(filtT + (size_t)id2 * 8);
        uint4 F3 = *(const uint4*)(filtT + (size_t)id3 * 8);
        acc[0] += v0 * bflo(F0.x) + v1 * bflo(F1.x) + v2 * bflo(F2.x) + v3 * bflo(F3.x);
        acc[1] += v0 * bfhi(F0.x) + v1 * bfhi(F1.x) + v2 * bfhi(F2.x) + v3 * bfhi(F3.x);
        acc[2] += v0 * bflo(F0.y) + v1 * bflo(F1.y) + v2 * bflo(F2.y) + v3 * bflo(F3.y);
        acc[3] += v0 * bfhi(F0.y) + v1 * bfhi(F1.y) + v2 * bfhi(F2.y) + v3 * bfhi(F3.y);
        acc[4] += v0 * bflo(F0.z) + v1 * bflo(F1.z) + v2 * bflo(F2.z) + v3 * bflo(F3.z);
        acc[5] += v0 * bfhi(F0.z) + v1 * bfhi(F1.z) + v2 * bfhi(F2.z) + v3 * bfhi(F3.z);
        acc[6] += v0 * bflo(F0.w) + v1 * bflo(F1.w) + v2 * bflo(F2.w) + v3 * bflo(F3.w);
        acc[7] += v0 * bfhi(F0.w) + v1 * bfhi(F1.w) + v2 * bfhi(F2.w) + v3 * bfhi(F3.w);
    }
    for (; i + 8 < e; i += 16) {
        int id0 = snp_ids[i];
        int id1 = snp_ids[i + 8];
        float v0 = bf1(snpT[(size_t)id0 * 16 + b]);
        float v1 = bf1(snpT[(size_t)id1 * 16 + b]);
        uint4 F0 = *(const uint4*)(filtT + (size_t)id0 * 8);
        uint4 F1 = *(const uint4*)(filtT + (size_t)id1 * 8);
        acc[0] += v0 * bflo(F0.x) + v1 * bflo(F1.x);
        acc[1] += v0 * bfhi(F0.x) + v1 * bfhi(F1.x);
        acc[2] += v0 * bflo(F0.y) + v1 * bflo(F1.y);
        acc[3] += v0 * bfhi(F0.y) + v1 * bfhi(F1.y);
        acc[4] += v0 * bflo(F0.z) + v1 * bflo(F1.z);
        acc[5] += v0 * bfhi(F0.z) + v1 * bfhi(F1.z);
        acc[6] += v0 * bflo(F0.w) + v1 * bflo(F1.w);
        acc[7] += v0 * bfhi(F0.w) + v1 * bfhi(F1.w);
    }
    if (i < e) {
        int id0 = snp_ids[i];
        float v0 = bf1(snpT[(size_t)id0 * 16 + b]);
        uint4 F0 = *(const uint4*)(filtT + (size_t)id0 * 8);
        acc[0] += v0 * bflo(F0.x); acc[1] += v0 * bfhi(F0.x);
        acc[2] += v0 * bflo(F0.y); acc[3] += v0 * bfhi(F0.y);
        acc[4] += v0 * bflo(F0.z); acc[5] += v0 * bfhi(F0.z);
        acc[6] += v0 * bflo(F0.w); acc[7] += v0 * bfhi(F0.w);
    }
    #pragma unroll
    for (int f = 0; f < 8; f++) {
        acc[f] += __shfl_xor(acc[f], 16, 64);
        acc[f] += __shfl_xor(acc[f], 32, 64);
    }
    if (lane < 16) {   // lane == b
        float* dst = &sZ[gidx][pair][lane * 8];
        *(float4*)(dst)     = make_float4(acc[0], acc[1], acc[2], acc[3]);
        *(float4*)(dst + 4) = make_float4(acc[4], acc[5], acc[6], acc[7]);
    }
    __syncthreads();
    {
        int half = t >> 7;                   // gene within block
        int c = t & 127;
        int gg = blockIdx.x * 2 + half;
        float val = sZ[half][0][c] + sZ[half][1][c];
        h_bf[(size_t)gg * 128 + c] = f2bf(val);
    }
}

// ---------------------------------------------------------------------------
// GIN aggregation (bf16), column-chunked: chunk = blockIdx&3 -> per-XCD L2
// slice is 1.28 MB (L2-resident). Block = 32 genes x 8 threads; each thread
// owns 4 bf16 (uint2 = 8B) of its chunk. Edge loop unrolled x8.
__global__ __launch_bounds__(256) void k_agg(const u16* __restrict__ hin,   // [g][128] bf16
                                             u16* __restrict__ z,           // [g][128] bf16
                                             const int* __restrict__ csr_off,
                                             const int* __restrict__ csr_src,
                                             const float* __restrict__ eps_l) {
    int t = threadIdx.x;
    int chunk = blockIdx.x & 3;
    int ggrp  = blockIdx.x >> 2;
    int g = ggrp * 32 + (t >> 3);
    int col = chunk * 32 + (t & 7) * 4;
    const u16* __restrict__ hc = hin + col;
    float epsv = 1.0f + eps_l[0];

    uint2 su = *(const uint2*)(hc + (size_t)g * 128);
    float a0 = bflo(su.x) * epsv, a1 = bfhi(su.x) * epsv;
    float a2 = bflo(su.y) * epsv, a3 = bfhi(su.y) * epsv;

    int s = csr_off[g], e = csr_off[g + 1];
    int k = s;
    for (; k + 7 < e; k += 8) {
        int i0 = csr_src[k];
        int i1 = csr_src[k + 1];
        int i2 = csr_src[k + 2];
        int i3 = csr_src[k + 3];
        int i4 = csr_src[k + 4];
        int i5 = csr_src[k + 5];
        int i6 = csr_src[k + 6];
        int i7 = csr_src[k + 7];
        uint2 v0 = *(const uint2*)(hc + (size_t)i0 * 128);
        uint2 v1 = *(const uint2*)(hc + (size_t)i1 * 128);
        uint2 v2 = *(const uint2*)(hc + (size_t)i2 * 128);
        uint2 v3 = *(const uint2*)(hc + (size_t)i3 * 128);
        uint2 v4 = *(const uint2*)(hc + (size_t)i4 * 128);
        uint2 v5 = *(const uint2*)(hc + (size_t)i5 * 128);
        uint2 v6 = *(const uint2*)(hc + (size_t)i6 * 128);
        uint2 v7 = *(const uint2*)(hc + (size_t)i7 * 128);
        a0 += ((bflo(v0.x) + bflo(v1.x)) + (bflo(v2.x) + bflo(v3.x)))
            + ((bflo(v4.x) + bflo(v5.x)) + (bflo(v6.x) + bflo(v7.x)));
        a1 += ((bfhi(v0.x) + bfhi(v1.x)) + (bfhi(v2.x) + bfhi(v3.x)))
            + ((bfhi(v4.x) + bfhi(v5.x)) + (bfhi(v6.x) + bfhi(v7.x)));
        a2 += ((bflo(v0.y) + bflo(v1.y)) + (bflo(v2.y) + bflo(v3.y)))
            + ((bflo(v4.y) + bflo(v5.y)) + (bflo(v6.y) + bflo(v7.y)));
        a3 += ((bfhi(v0.y) + bfhi(v1.y)) + (bfhi(v2.y) + bfhi(v3.y)))
            + ((bfhi(v4.y) + bfhi(v5.y)) + (bfhi(v6.y) + bfhi(v7.y)));
    }
    for (; k + 1 < e; k += 2) {
        int i0 = csr_src[k];
        int i1 = csr_src[k + 1];
        uint2 v0 = *(const uint2*)(hc + (size_t)i0 * 128);
        uint2 v1 = *(const uint2*)(hc + (size_t)i1 * 128);
        a0 += bflo(v0.x) + bflo(v1.x);
        a1 += bfhi(v0.x) + bfhi(v1.x);
        a2 += bflo(v0.y) + bflo(v1.y);
        a3 += bfhi(v0.y) + bfhi(v1.y);
    }
    if (k < e) {
        int i0 = csr_src[k];
        uint2 v0 = *(const uint2*)(hc + (size_t)i0 * 128);
        a0 += bflo(v0.x); a1 += bfhi(v0.x);
        a2 += bflo(v0.y); a3 += bfhi(v0.y);
    }
    uint2 o;
    o.x = pack2(a0, a1);
    o.y = pack2(a2, a3);
    *(uint2*)(z + (size_t)g * 128 + col) = o;
}

// ---------------------------------------------------------------------------
// GIN MLP over 320k rows (row r = g*16+b), bf16 in/out, fp32 compute.
__global__ __launch_bounds__(256) void k_mlp(const u16* __restrict__ z,
                                             u16* __restrict__ hout,
                                             const float* __restrict__ W1,
                                             const float* __restrict__ b1,
                                             const float* __restrict__ g1,
                                             const float* __restrict__ bt1,
                                             const float* __restrict__ W2,
                                             const float* __restrict__ b2,
                                             const float* __restrict__ g2,
                                             const float* __restrict__ bt2) {
    __shared__ float sW1[128], sb1[16], sg1[16], sbt1[16];
    __shared__ float sW2[128], sb2[8], sg2[8], sbt2[8];
    int t = threadIdx.x;
    if (t < 128) { sW1[t] = W1[t]; sW2[t] = W2[t]; }
    if (t < 16)  { sb1[t] = b1[t]; sg1[t] = g1[t]; sbt1[t] = bt1[t]; }
    if (t < 8)   { sb2[t] = b2[t]; sg2[t] = g2[t]; sbt2[t] = bt2[t]; }
    __syncthreads();

    size_t r = (size_t)blockIdx.x * 256 + t;     // 0 .. 320000
    uint4 zu = *(const uint4*)(z + r * 8);
    float zz[8] = { bflo(zu.x), bfhi(zu.x), bflo(zu.y), bfhi(zu.y),
                    bflo(zu.z), bfhi(zu.z), bflo(zu.w), bfhi(zu.w) };

    float o[8];
    #pragma unroll
    for (int f = 0; f < 8; f++) o[f] = sb2[f];
    #pragma unroll
    for (int j = 0; j < 16; j++) {
        float s1 = sb1[j];
        #pragma unroll
        for (int i = 0; i < 8; i++) s1 += zz[i] * sW1[i * 16 + j];
        s1 = s1 * BN_SCALE * sg1[j] + sbt1[j];
        s1 = gelu_erf(s1);
        #pragma unroll
        for (int f = 0; f < 8; f++) o[f] += s1 * sW2[j * 8 + f];
    }
    uint4 ou;
    float r0 = gelu_erf(o[0] * BN_SCALE * sg2[0] + sbt2[0]);
    float r1 = gelu_erf(o[1] * BN_SCALE * sg2[1] + sbt2[1]);
    float r2 = gelu_erf(o[2] * BN_SCALE * sg2[2] + sbt2[2]);
    float r3 = gelu_erf(o[3] * BN_SCALE * sg2[3] + sbt2[3]);
    float r4 = gelu_erf(o[4] * BN_SCALE * sg2[4] + sbt2[4]);
    float r5 = gelu_erf(o[5] * BN_SCALE * sg2[5] + sbt2[5]);
    float r6 = gelu_erf(o[6] * BN_SCALE * sg2[6] + sbt2[6]);
    float r7 = gelu_erf(o[7] * BN_SCALE * sg2[7] + sbt2[7]);
    ou.x = pack2(r0, r1); ou.y = pack2(r2, r3);
    ou.z = pack2(r4, r5); ou.w = pack2(r6, r7);
    *(uint4*)(hout + r * 8) = ou;
}

// ---------------------------------------------------------------------------
// Attentive readout, gene-major bf16 input. Block = 256 = 16 genes x 16 b.
__global__ __launch_bounds__(256) void k_readout_gm(const u16* __restrict__ h,  // [g][128] bf16
                                                    const float* __restrict__ Wk,
                                                    const float* __restrict__ bk,
                                                    const float* __restrict__ Wq,
                                                    const float* __restrict__ Wv,
                                                    const float* __restrict__ bv,
                                                    float* __restrict__ w_out,   // [b][g]
                                                    float* __restrict__ g_h) {
    __shared__ float sWk[64], sWv[64], sbk[8], sbv[8], sWq[8];
    __shared__ float sRed[4][16][8];
    __shared__ float sWout[16][17];
    int t = threadIdx.x;
    if (t < 64) { sWk[t] = Wk[t]; sWv[t] = Wv[t]; }
    if (t < 8)  { sbk[t] = bk[t]; sbv[t] = bv[t]; sWq[t] = Wq[t]; }
    __syncthreads();

    int gs = t >> 4;
    int b  = t & 15;
    int g  = blockIdx.x * 16 + gs;

    uint4 hu = *(const uint4*)(h + (size_t)g * 128 + b * 8);
    float hv[8] = { bflo(hu.x), bfhi(hu.x), bflo(hu.y), bfhi(hu.y),
                    bflo(hu.z), bfhi(hu.z), bflo(hu.w), bfhi(hu.w) };

    float q = 0.0f;
    #pragma unroll
    for (int j = 0; j < 8; j++) {
        float key = sbk[j];
        #pragma unroll
        for (int i = 0; i < 8; i++) key += hv[i] * sWk[i * 8 + j];
        q += key * sWq[j];
    }
    float w = sigmoidf_(q);
    sWout[gs][b] = w;

    float contrib[8];
    #pragma unroll
    for (int f = 0; f < 8; f++) {
        float v = sbv[f];
        #pragma unroll
        for (int i = 0; i < 8; i++) v += hv[i] * sWv[i * 8 + f];
        contrib[f] = v * w;
    }
    #pragma unroll
    for (int f = 0; f < 8; f++) {
        contrib[f] += __shfl_xor(contrib[f], 16, 64);
        contrib[f] += __shfl_xor(contrib[f], 32, 64);
    }
    int wave = t >> 6, lane = t & 63;
    if (lane < 16) {
        #pragma unroll
        for (int f = 0; f < 8; f++) sRed[wave][lane][f] = contrib[f];
    }
    __syncthreads();
    if (t < 128) {
        int bb = t >> 3, f = t & 7;
        float s = sRed[0][bb][f] + sRed[1][bb][f] + sRed[2][bb][f] + sRed[3][bb][f];
        atomicAdd(&g_h[bb * 8 + f], s);
    }
    {
        int bb = t >> 4, gi = t & 15;
        w_out[(size_t)bb * NGENES + blockIdx.x * 16 + gi] = sWout[gi][bb];
    }
}

// ---------------------------------------------------------------------------
__global__ __launch_bounds__(1024) void k_head(const float* __restrict__ g_h,
                                               const float* __restrict__ Wp1, const float* __restrict__ bp1,
                                               const float* __restrict__ gp1, const float* __restrict__ btp1,
                                               const float* __restrict__ Wp2, const float* __restrict__ bp2,
                                               const float* __restrict__ gp2, const float* __restrict__ btp2,
                                               const float* __restrict__ Wp3, const float* __restrict__ bp3,
                                               float* __restrict__ preds) {
    __shared__ float sgh[128];
    __shared__ float z1[16 * 64];
    __shared__ float z2[16 * 16];
    int t = threadIdx.x;
    if (t < 128) sgh[t] = g_h[t];
    __syncthreads();
    {
        int b = t >> 6, j = t & 63;
        float s = bp1[j];
        #pragma unroll
        for (int k = 0; k < 8; k++) s += sgh[b * 8 + k] * Wp1[k * 64 + j];
        s = s * BN_SCALE * gp1[j] + btp1[j];
        z1[b * 64 + j] = gelu_erf(s);
    }
    __syncthreads();
    if (t < 256) {
        int b = t >> 4, j = t & 15;
        float s = bp2[j];
        for (int k = 0; k < 64; k++) s += z1[b * 64 + k] * Wp2[k * 16 + j];
        s = s * BN_SCALE * gp2[j] + btp2[j];
        z2[b * 16 + j] = gelu_erf(s);
    }
    __syncthreads();
    if (t < 16) {
        float s = bp3[0];
        #pragma unroll
        for (int k = 0; k < 16; k++) s += z2[t * 16 + k] * Wp3[k];
        preds[t] = s;
    }
}

// ---------------------------------------------------------------------------
extern "C" void kernel_launch(void* const* d_in, const int* in_sizes, int n_in,
                              void* d_out, int out_size, void* d_ws, size_t ws_size,
                              hipStream_t stream) {
    const float* snp          = (const float*)d_in[0];
    const int*   snp_ids      = (const int*)  d_in[1];
    const int*   gene_of_node = (const int*)  d_in[2];
    const int*   edge_src     = (const int*)  d_in[3];
    const int*   edge_dst     = (const int*)  d_in[4];
    const float* filters      = (const float*)d_in[5];
    const float* eps          = (const float*)d_in[6];
    const float* W1  = (const float*)d_in[7];
    const float* b1  = (const float*)d_in[8];
    const float* g1  = (const float*)d_in[9];
    const float* bt1 = (const float*)d_in[10];
    const float* W2  = (const float*)d_in[11];
    const float* b2  = (const float*)d_in[12];
    const float* g2  = (const float*)d_in[13];
    const float* bt2 = (const float*)d_in[14];
    const float* Wk  = (const float*)d_in[15];
    const float* bk  = (const float*)d_in[16];
    const float* Wq  = (const float*)d_in[17];
    const float* Wv  = (const float*)d_in[18];
    const float* bv  = (const float*)d_in[19];
    const float* Wp1 = (const float*)d_in[20];
    const float* bp1 = (const float*)d_in[21];
    const float* gp1 = (const float*)d_in[22];
    const float* btp1= (const float*)d_in[23];
    const float* Wp2 = (const float*)d_in[24];
    const float* bp2 = (const float*)d_in[25];
    const float* gp2 = (const float*)d_in[26];
    const float* btp2= (const float*)d_in[27];
    const float* Wp3 = (const float*)d_in[28];
    const float* bp3 = (const float*)d_in[29];

    float* out        = (float*)d_out;
    float* out_preds  = out;
    float* out_filt   = out + 16;
    float* out_w      = out + 16 + NFILT * NSNPS;

    // ---- workspace layout (all bf16 intermediates; no aliasing needed)
    char* ws = (char*)d_ws;
    size_t off = 0;
    u16* snpT = (u16*)(ws + off); off += (size_t)NSNPS * 16 * 2;                 // 16 MB
    u16* filtT= (u16*)(ws + off); off += (size_t)NSNPS * 8 * 2;                  // 8 MB
    u16* h0   = (u16*)(ws + off); off += (size_t)NGENES * 128 * 2;               // 5.12 MB
    u16* h1   = (u16*)(ws + off); off += (size_t)NGENES * 128 * 2;               // 5.12 MB
    u16* zbuf = (u16*)(ws + off); off += (size_t)NGENES * 128 * 2;               // 5.12 MB
    int* node_off = (int*)(ws + off); off += ((NGENES + 1) * 4 + 255) / 256 * 256;
    int* deg      = (int*)(ws + off); off += (NGENES * 4 + 255) / 256 * 256;
    int* csr_off  = (int*)(ws + off); off += ((NGENES + 1) * 4 + 255) / 256 * 256;
    int* cursor   = (int*)(ws + off); off += (NGENES * 4 + 255) / 256 * 256;
    int* csr_src  = (int*)(ws + off); off += (size_t)NEDGES * 4;
    float* g_h    = (float*)(ws + off); off += 256;

    // 1. fused prep: filtersT(bf16) + snpT(bf16) + node_off/zero + filters copy
    k_prep<<<PREP_NA + PREP_NB + PREP_NC + PREP_NE, 256, 0, stream>>>(
        snp, filters, gene_of_node, snpT, filtT, (float4*)out_filt,
        node_off, deg, g_h);
    // 2. CSR build
    k_deg<<<(NEDGES + 255) / 256, 256, 0, stream>>>(edge_dst, deg);
    k_scan<<<1, 1024, 0, stream>>>(deg, csr_off, cursor);
    k_scatter<<<(NEDGES + 255) / 256, 256, 0, stream>>>(edge_src, edge_dst, cursor, csr_src);
    // 3. SNP -> gene readout (bf16, gene-major)
    k_snp2gene<<<NGENES / 2, 256, 0, stream>>>(snpT, snp_ids, node_off, filtT, h0);
    // 4. GIN layers: agg (L2-chunked bf16) + mlp (streaming)
    k_agg<<<(NGENES / 32) * 4, 256, 0, stream>>>(h0, zbuf, csr_off, csr_src, eps + 0);
    k_mlp<<<NGENES * BB / 256, 256, 0, stream>>>(zbuf, h1,
                                                 W1 + 0 * 128, b1 + 0 * 16, g1 + 0 * 16, bt1 + 0 * 16,
                                                 W2 + 0 * 128, b2 + 0 * 8, g2 + 0 * 8, bt2 + 0 * 8);
    k_agg<<<(NGENES / 32) * 4, 256, 0, stream>>>(h1, zbuf, csr_off, csr_src, eps + 1);
    k_mlp<<<NGENES * BB / 256, 256, 0, stream>>>(zbuf, h0,
                                                 W1 + 1 * 128, b1 + 1 * 16, g1 + 1 * 16, bt1 + 1 * 16,
                                                 W2 + 1 * 128, b2 + 1 * 8, g2 + 1 * 8, bt2 + 1 * 8);
    // 5. attentive readout
    k_readout_gm<<<NGENES / 16, 256, 0, stream>>>(h0, Wk, bk, Wq, Wv, bv, out_w, g_h);
    // 6. head MLP
    k_head<<<1, 1024, 0, stream>>>(g_h, Wp1, bp1, gp1, btp1, Wp2, bp2, gp2, btp2, Wp3, bp3, out_preds);
}

// Round 7
// 355.160 us; speedup vs baseline: 1.4840x; 1.0049x over previous
//
#include <hip/hip_runtime.h>
#include <math.h>

#define NSNPS  500000
#define NGENES 20000
#define NNODES 600000
#define NEDGES 320000
#define BB     16
#define NFILT  8

// rsqrt(1 + 1e-5)
#define BN_SCALE 0.99999500003749968f

typedef unsigned short u16;

__device__ __forceinline__ float gelu_erf(float x) {
    return 0.5f * x * (1.0f + erff(x * 0.70710678118654752f));
}
__device__ __forceinline__ float sigmoidf_(float x) {
    return 1.0f / (1.0f + expf(-x));
}
// fp32 -> bf16 round-to-nearest-even
__device__ __forceinline__ u16 f2bf(float x) {
    unsigned u = __float_as_uint(x);
    u += 0x7fffu + ((u >> 16) & 1u);
    return (u16)(u >> 16);
}
__device__ __forceinline__ float bf1(u16 v)      { return __uint_as_float(((unsigned)v) << 16); }
__device__ __forceinline__ float bflo(unsigned v){ return __uint_as_float(v << 16); }
__device__ __forceinline__ float bfhi(unsigned v){ return __uint_as_float(v & 0xffff0000u); }
__device__ __forceinline__ unsigned pack2(float a, float b) {
    return (unsigned)f2bf(a) | ((unsigned)f2bf(b) << 16);
}

// ---------------------------------------------------------------------------
// Fused prep:
//  [A] filtersT bf16 + fp32 filters passthrough copy (one read of filters)
//  [B] snpT bf16
//  [C] node_off binary search + zero deg/g_h
#define PREP_NA 1954   // ceil(NSNPS/256)
#define PREP_NB 1954
#define PREP_NC 79     // ceil((NGENES+1)/256)
__global__ __launch_bounds__(256) void k_prep(const float* __restrict__ snp,
                                              const float* __restrict__ filters,
                                              const int* __restrict__ gene_of_node,
                                              u16* __restrict__ snpT,
                                              u16* __restrict__ filtT,
                                              float* __restrict__ out_filt,
                                              int* __restrict__ node_off,
                                              int* __restrict__ deg,
                                              float* __restrict__ g_h) {
    int bid = blockIdx.x;
    int t = threadIdx.x;
    if (bid < PREP_NA) {
        int n = bid * 256 + t;
        if (n < NSNPS) {
            float f0 = filters[0 * NSNPS + n], f1 = filters[1 * NSNPS + n];
            float f2 = filters[2 * NSNPS + n], f3 = filters[3 * NSNPS + n];
            float f4 = filters[4 * NSNPS + n], f5 = filters[5 * NSNPS + n];
            float f6 = filters[6 * NSNPS + n], f7 = filters[7 * NSNPS + n];
            uint4 p;
            p.x = pack2(f0, f1); p.y = pack2(f2, f3);
            p.z = pack2(f4, f5); p.w = pack2(f6, f7);
            *(uint4*)(filtT + (size_t)n * 8) = p;
            out_filt[0 * NSNPS + n] = f0; out_filt[1 * NSNPS + n] = f1;
            out_filt[2 * NSNPS + n] = f2; out_filt[3 * NSNPS + n] = f3;
            out_filt[4 * NSNPS + n] = f4; out_filt[5 * NSNPS + n] = f5;
            out_filt[6 * NSNPS + n] = f6; out_filt[7 * NSNPS + n] = f7;
        }
    } else if (bid < PREP_NA + PREP_NB) {
        int n = (bid - PREP_NA) * 256 + t;
        if (n < NSNPS) {
            uint4 p0, p1;
            p0.x = pack2(snp[0 * (size_t)NSNPS + n],  snp[1 * (size_t)NSNPS + n]);
            p0.y = pack2(snp[2 * (size_t)NSNPS + n],  snp[3 * (size_t)NSNPS + n]);
            p0.z = pack2(snp[4 * (size_t)NSNPS + n],  snp[5 * (size_t)NSNPS + n]);
            p0.w = pack2(snp[6 * (size_t)NSNPS + n],  snp[7 * (size_t)NSNPS + n]);
            p1.x = pack2(snp[8 * (size_t)NSNPS + n],  snp[9 * (size_t)NSNPS + n]);
            p1.y = pack2(snp[10 * (size_t)NSNPS + n], snp[11 * (size_t)NSNPS + n]);
            p1.z = pack2(snp[12 * (size_t)NSNPS + n], snp[13 * (size_t)NSNPS + n]);
            p1.w = pack2(snp[14 * (size_t)NSNPS + n], snp[15 * (size_t)NSNPS + n]);
            uint4* dst = (uint4*)(snpT + (size_t)n * 16);
            dst[0] = p0; dst[1] = p1;
        }
    } else {
        int g = (bid - PREP_NA - PREP_NB) * 256 + t;
        if (g < NGENES) deg[g] = 0;
        if (g < BB * NFILT) g_h[g] = 0.0f;
        if (g <= NGENES) {
            int lo = 0, hi = NNODES;
            while (lo < hi) {
                int mid = (lo + hi) >> 1;
                if (gene_of_node[mid] < g) lo = mid + 1; else hi = mid;
            }
            node_off[g] = lo;
        }
    }
}

// ---------------------------------------------------------------------------
__global__ __launch_bounds__(256) void k_deg(const int* __restrict__ edge_dst,
                                             int* __restrict__ deg) {
    int e = blockIdx.x * 256 + threadIdx.x;
    if (e >= NEDGES) return;
    atomicAdd(&deg[edge_dst[e]], 1);
}

__global__ __launch_bounds__(1024) void k_scan(const int* __restrict__ deg,
                                               int* __restrict__ csr_off,
                                               int* __restrict__ cursor) {
    __shared__ int sums[1024];
    int t = threadIdx.x;
    const int CH = (NGENES + 1023) / 1024;   // 20
    int base = t * CH;
    int s = 0;
    for (int i = 0; i < CH; i++) {
        int idx = base + i;
        if (idx < NGENES) s += deg[idx];
    }
    sums[t] = s;
    __syncthreads();
    for (int off = 1; off < 1024; off <<= 1) {
        int v = (t >= off) ? sums[t - off] : 0;
        __syncthreads();
        sums[t] += v;
        __syncthreads();
    }
    int run = (t == 0) ? 0 : sums[t - 1];
    for (int i = 0; i < CH; i++) {
        int idx = base + i;
        if (idx < NGENES) {
            csr_off[idx] = run;
            cursor[idx]  = run;
            run += deg[idx];
        }
    }
    if (t == 1023) csr_off[NGENES] = sums[1023];
}

__global__ __launch_bounds__(256) void k_scatter(const int* __restrict__ edge_src,
                                                 const int* __restrict__ edge_dst,
                                                 int* __restrict__ cursor,
                                                 int* __restrict__ csr_src) {
    int e = blockIdx.x * 256 + threadIdx.x;
    if (e >= NEDGES) return;
    int p = atomicAdd(&cursor[edge_dst[e]], 1);
    csr_src[p] = edge_src[e];
}

// ---------------------------------------------------------------------------
// SNP->gene (bf16): TWO waves per gene, 2 genes per block. lane = sub4*16 + b.
__global__ __launch_bounds__(256) void k_snp2gene(const u16* __restrict__ snpT,
                                                  const int* __restrict__ snp_ids,
                                                  const int* __restrict__ node_off,
                                                  const u16* __restrict__ filtT,
                                                  u16* __restrict__ h_bf) {
    __shared__ float sZ[2][2][128];
    int t = threadIdx.x;
    int waveIdx = t >> 6, lane = t & 63;
    int gidx = waveIdx >> 1;
    int pair = waveIdx & 1;
    int g = blockIdx.x * 2 + gidx;
    int sub = (pair << 2) + (lane >> 4);     // 0..7
    int b = lane & 15;
    int s = node_off[g], e = node_off[g + 1];

    float acc[8];
    #pragma unroll
    for (int f = 0; f < 8; f++) acc[f] = 0.0f;

    int i = s + sub;
    for (; i + 24 < e; i += 32) {
        int id0 = snp_ids[i];
        int id1 = snp_ids[i + 8];
        int id2 = snp_ids[i + 16];
        int id3 = snp_ids[i + 24];
        float v0 = bf1(snpT[(size_t)id0 * 16 + b]);
        float v1 = bf1(snpT[(size_t)id1 * 16 + b]);
        float v2 = bf1(snpT[(size_t)id2 * 16 + b]);
        float v3 = bf1(snpT[(size_t)id3 * 16 + b]);
        uint4 F0 = *(const uint4*)(filtT + (size_t)id0 * 8);
        uint4 F1 = *(const uint4*)(filtT + (size_t)id1 * 8);
        uint4 F2 = *(const uint4*)(filtT + (size_t)id2 * 8);
        uint4 F3 = *(const uint4*)(filtT + (size_t)id3 * 8);
        acc[0] += v0 * bflo(F0.x) + v1 * bflo(F1.x) + v2 * bflo(F2.x) + v3 * bflo(F3.x);
        acc[1] += v0 * bfhi(F0.x) + v1 * bfhi(F1.x) + v2 * bfhi(F2.x) + v3 * bfhi(F3.x);
        acc[2] += v0 * bflo(F0.y) + v1 * bflo(F1.y) + v2 * bflo(F2.y) + v3 * bflo(F3.y);
        acc[3] += v0 * bfhi(F0.y) + v1 * bfhi(F1.y) + v2 * bfhi(F2.y) + v3 * bfhi(F3.y);
        acc[4] += v0 * bflo(F0.z) + v1 * bflo(F1.z) + v2 * bflo(F2.z) + v3 * bflo(F3.z);
        acc[5] += v0 * bfhi(F0.z) + v1 * bfhi(F1.z) + v2 * bfhi(F2.z) + v3 * bfhi(F3.z);
        acc[6] += v0 * bflo(F0.w) + v1 * bflo(F1.w) + v2 * bflo(F2.w) + v3 * bflo(F3.w);
        acc[7] += v0 * bfhi(F0.w) + v1 * bfhi(F1.w) + v2 * bfhi(F2.w) + v3 * bfhi(F3.w);
    }
    for (; i + 8 < e; i += 16) {
        int id0 = snp_ids[i];
        int id1 = snp_ids[i + 8];
        float v0 = bf1(snpT[(size_t)id0 * 16 + b]);
        float v1 = bf1(snpT[(size_t)id1 * 16 + b]);
        uint4 F0 = *(const uint4*)(filtT + (size_t)id0 * 8);
        uint4 F1 = *(const uint4*)(filtT + (size_t)id1 * 8);
        acc[0] += v0 * bflo(F0.x) + v1 * bflo(F1.x);
        acc[1] += v0 * bfhi(F0.x) + v1 * bfhi(F1.x);
        acc[2] += v0 * bflo(F0.y) + v1 * bflo(F1.y);
        acc[3] += v0 * bfhi(F0.y) + v1 * bfhi(F1.y);
        acc[4] += v0 * bflo(F0.z) + v1 * bflo(F1.z);
        acc[5] += v0 * bfhi(F0.z) + v1 * bfhi(F1.z);
        acc[6] += v0 * bflo(F0.w) + v1 * bflo(F1.w);
        acc[7] += v0 * bfhi(F0.w) + v1 * bfhi(F1.w);
    }
    if (i < e) {
        int id0 = snp_ids[i];
        float v0 = bf1(snpT[(size_t)id0 * 16 + b]);
        uint4 F0 = *(const uint4*)(filtT + (size_t)id0 * 8);
        acc[0] += v0 * bflo(F0.x); acc[1] += v0 * bfhi(F0.x);
        acc[2] += v0 * bflo(F0.y); acc[3] += v0 * bfhi(F0.y);
        acc[4] += v0 * bflo(F0.z); acc[5] += v0 * bfhi(F0.z);
        acc[6] += v0 * bflo(F0.w); acc[7] += v0 * bfhi(F0.w);
    }
    #pragma unroll
    for (int f = 0; f < 8; f++) {
        acc[f] += __shfl_xor(acc[f], 16, 64);
        acc[f] += __shfl_xor(acc[f], 32, 64);
    }
    if (lane < 16) {
        float* dst = &sZ[gidx][pair][lane * 8];
        *(float4*)(dst)     = make_float4(acc[0], acc[1], acc[2], acc[3]);
        *(float4*)(dst + 4) = make_float4(acc[4], acc[5], acc[6], acc[7]);
    }
    __syncthreads();
    {
        int half = t >> 7;
        int c = t & 127;
        int gg = blockIdx.x * 2 + half;
        float val = sZ[half][0][c] + sZ[half][1][c];
        h_bf[(size_t)gg * 128 + c] = f2bf(val);
    }
}

// ---------------------------------------------------------------------------
// Fused GIN layer 1: chunked agg (bf16, L2-resident per-XCD slice) + MLP.
// Block = 32 genes x 8 subs; chunk = blockIdx&3. Thread owns 4 cols (half a
// (g,b) row); pair-exchange via shfl_xor(1) gives the full row for the MLP.
__global__ __launch_bounds__(256) void k_gin1(const u16* __restrict__ hin,   // [g][128]
                                              u16* __restrict__ hout,        // [g][128]
                                              const int* __restrict__ csr_off,
                                              const int* __restrict__ csr_src,
                                              const float* __restrict__ eps_l,
                                              const float* __restrict__ W1,
                                              const float* __restrict__ b1,
                                              const float* __restrict__ g1,
                                              const float* __restrict__ bt1,
                                              const float* __restrict__ W2,
                                              const float* __restrict__ b2,
                                              const float* __restrict__ g2,
                                              const float* __restrict__ bt2) {
    __shared__ float sW1[128], sb1[16], sg1[16], sbt1[16];
    __shared__ float sW2[128], sb2[8], sg2[8], sbt2[8];
    int t = threadIdx.x;
    if (t < 128) { sW1[t] = W1[t]; sW2[t] = W2[t]; }
    if (t < 16)  { sb1[t] = b1[t]; sg1[t] = g1[t]; sbt1[t] = bt1[t]; }
    if (t < 8)   { sb2[t] = b2[t]; sg2[t] = g2[t]; sbt2[t] = bt2[t]; }

    int chunk = blockIdx.x & 3;
    int g = (blockIdx.x >> 2) * 32 + (t >> 3);
    int col = chunk * 32 + (t & 7) * 4;
    int fh = (t & 7) & 1;                    // f-half: 0 -> f0..3, 1 -> f4..7
    const u16* __restrict__ hc = hin + col;
    float epsv = 1.0f + eps_l[0];

    uint2 su = *(const uint2*)(hc + (size_t)g * 128);
    float a0 = bflo(su.x) * epsv, a1 = bfhi(su.x) * epsv;
    float a2 = bflo(su.y) * epsv, a3 = bfhi(su.y) * epsv;

    int s = csr_off[g], e = csr_off[g + 1];
    int k = s;
    for (; k + 7 < e; k += 8) {
        int i0 = csr_src[k],     i1 = csr_src[k + 1];
        int i2 = csr_src[k + 2], i3 = csr_src[k + 3];
        int i4 = csr_src[k + 4], i5 = csr_src[k + 5];
        int i6 = csr_src[k + 6], i7 = csr_src[k + 7];
        uint2 v0 = *(const uint2*)(hc + (size_t)i0 * 128);
        uint2 v1 = *(const uint2*)(hc + (size_t)i1 * 128);
        uint2 v2 = *(const uint2*)(hc + (size_t)i2 * 128);
        uint2 v3 = *(const uint2*)(hc + (size_t)i3 * 128);
        uint2 v4 = *(const uint2*)(hc + (size_t)i4 * 128);
        uint2 v5 = *(const uint2*)(hc + (size_t)i5 * 128);
        uint2 v6 = *(const uint2*)(hc + (size_t)i6 * 128);
        uint2 v7 = *(const uint2*)(hc + (size_t)i7 * 128);
        a0 += ((bflo(v0.x) + bflo(v1.x)) + (bflo(v2.x) + bflo(v3.x)))
            + ((bflo(v4.x) + bflo(v5.x)) + (bflo(v6.x) + bflo(v7.x)));
        a1 += ((bfhi(v0.x) + bfhi(v1.x)) + (bfhi(v2.x) + bfhi(v3.x)))
            + ((bfhi(v4.x) + bfhi(v5.x)) + (bfhi(v6.x) + bfhi(v7.x)));
        a2 += ((bflo(v0.y) + bflo(v1.y)) + (bflo(v2.y) + bflo(v3.y)))
            + ((bflo(v4.y) + bflo(v5.y)) + (bflo(v6.y) + bflo(v7.y)));
        a3 += ((bfhi(v0.y) + bfhi(v1.y)) + (bfhi(v2.y) + bfhi(v3.y)))
            + ((bfhi(v4.y) + bfhi(v5.y)) + (bfhi(v6.y) + bfhi(v7.y)));
    }
    for (; k + 1 < e; k += 2) {
        int i0 = csr_src[k], i1 = csr_src[k + 1];
        uint2 v0 = *(const uint2*)(hc + (size_t)i0 * 128);
        uint2 v1 = *(const uint2*)(hc + (size_t)i1 * 128);
        a0 += bflo(v0.x) + bflo(v1.x);
        a1 += bfhi(v0.x) + bfhi(v1.x);
        a2 += bflo(v0.y) + bflo(v1.y);
        a3 += bfhi(v0.y) + bfhi(v1.y);
    }
    if (k < e) {
        int i0 = csr_src[k];
        uint2 v0 = *(const uint2*)(hc + (size_t)i0 * 128);
        a0 += bflo(v0.x); a1 += bfhi(v0.x);
        a2 += bflo(v0.y); a3 += bfhi(v0.y);
    }
    __syncthreads();   // weights visible

    // exchange halves with the pair thread (t ^ 1, same gene, same batch)
    float p0 = __shfl_xor(a0, 1, 64);
    float p1 = __shfl_xor(a1, 1, 64);
    float p2 = __shfl_xor(a2, 1, 64);
    float p3 = __shfl_xor(a3, 1, 64);
    float z[8];
    z[fh * 4 + 0] = a0; z[fh * 4 + 1] = a1; z[fh * 4 + 2] = a2; z[fh * 4 + 3] = a3;
    z[(1 - fh) * 4 + 0] = p0; z[(1 - fh) * 4 + 1] = p1;
    z[(1 - fh) * 4 + 2] = p2; z[(1 - fh) * 4 + 3] = p3;

    float o[8];
    #pragma unroll
    for (int f = 0; f < 8; f++) o[f] = sb2[f];
    #pragma unroll
    for (int j = 0; j < 16; j++) {
        float s1 = sb1[j];
        #pragma unroll
        for (int i2 = 0; i2 < 8; i2++) s1 += z[i2] * sW1[i2 * 16 + j];
        s1 = s1 * BN_SCALE * sg1[j] + sbt1[j];
        s1 = gelu_erf(s1);
        #pragma unroll
        for (int f = 0; f < 8; f++) o[f] += s1 * sW2[j * 8 + f];
    }
    float r0 = gelu_erf(o[fh * 4 + 0] * BN_SCALE * sg2[fh * 4 + 0] + sbt2[fh * 4 + 0]);
    float r1 = gelu_erf(o[fh * 4 + 1] * BN_SCALE * sg2[fh * 4 + 1] + sbt2[fh * 4 + 1]);
    float r2 = gelu_erf(o[fh * 4 + 2] * BN_SCALE * sg2[fh * 4 + 2] + sbt2[fh * 4 + 2]);
    float r3 = gelu_erf(o[fh * 4 + 3] * BN_SCALE * sg2[fh * 4 + 3] + sbt2[fh * 4 + 3]);
    uint2 ou;
    ou.x = pack2(r0, r1); ou.y = pack2(r2, r3);
    *(uint2*)(hout + (size_t)g * 128 + col) = ou;
}

// ---------------------------------------------------------------------------
// Fused GIN layer 2 + attentive readout. Same structure as k_gin1 but instead
// of storing h, computes w = sigmoid(key(h)@Wq) and g_h += value(h)*w.
__global__ __launch_bounds__(256) void k_gin2(const u16* __restrict__ hin,
                                              const int* __restrict__ csr_off,
                                              const int* __restrict__ csr_src,
                                              const float* __restrict__ eps_l,
                                              const float* __restrict__ W1,
                                              const float* __restrict__ b1,
                                              const float* __restrict__ g1,
                                              const float* __restrict__ bt1,
                                              const float* __restrict__ W2,
                                              const float* __restrict__ b2,
                                              const float* __restrict__ g2,
                                              const float* __restrict__ bt2,
                                              const float* __restrict__ Wk,
                                              const float* __restrict__ bk,
                                              const float* __restrict__ Wq,
                                              const float* __restrict__ Wv,
                                              const float* __restrict__ bv,
                                              float* __restrict__ w_out,   // [b][g]
                                              float* __restrict__ g_h) {
    __shared__ float sW1[128], sb1[16], sg1[16], sbt1[16];
    __shared__ float sW2[128], sb2[8], sg2[8], sbt2[8];
    __shared__ float sWk[64], sWv[64], sbk[8], sbv[8], sWq[8];
    __shared__ float sRed[4][4][8];
    int t = threadIdx.x;
    if (t < 128) { sW1[t] = W1[t]; sW2[t] = W2[t]; }
    if (t < 64)  { sWk[t] = Wk[t]; sWv[t] = Wv[t]; }
    if (t < 16)  { sb1[t] = b1[t]; sg1[t] = g1[t]; sbt1[t] = bt1[t]; }
    if (t < 8)   { sb2[t] = b2[t]; sg2[t] = g2[t]; sbt2[t] = bt2[t];
                   sbk[t] = bk[t]; sbv[t] = bv[t]; sWq[t] = Wq[t]; }

    int chunk = blockIdx.x & 3;
    int g = (blockIdx.x >> 2) * 32 + (t >> 3);
    int col = chunk * 32 + (t & 7) * 4;
    int fh = (t & 7) & 1;
    int b = chunk * 4 + ((t & 7) >> 1);      // global batch for this row
    const u16* __restrict__ hc = hin + col;
    float epsv = 1.0f + eps_l[0];

    uint2 su = *(const uint2*)(hc + (size_t)g * 128);
    float a0 = bflo(su.x) * epsv, a1 = bfhi(su.x) * epsv;
    float a2 = bflo(su.y) * epsv, a3 = bfhi(su.y) * epsv;

    int s = csr_off[g], e = csr_off[g + 1];
    int k = s;
    for (; k + 7 < e; k += 8) {
        int i0 = csr_src[k],     i1 = csr_src[k + 1];
        int i2 = csr_src[k + 2], i3 = csr_src[k + 3];
        int i4 = csr_src[k + 4], i5 = csr_src[k + 5];
        int i6 = csr_src[k + 6], i7 = csr_src[k + 7];
        uint2 v0 = *(const uint2*)(hc + (size_t)i0 * 128);
        uint2 v1 = *(const uint2*)(hc + (size_t)i1 * 128);
        uint2 v2 = *(const uint2*)(hc + (size_t)i2 * 128);
        uint2 v3 = *(const uint2*)(hc + (size_t)i3 * 128);
        uint2 v4 = *(const uint2*)(hc + (size_t)i4 * 128);
        uint2 v5 = *(const uint2*)(hc + (size_t)i5 * 128);
        uint2 v6 = *(const uint2*)(hc + (size_t)i6 * 128);
        uint2 v7 = *(const uint2*)(hc + (size_t)i7 * 128);
        a0 += ((bflo(v0.x) + bflo(v1.x)) + (bflo(v2.x) + bflo(v3.x)))
            + ((bflo(v4.x) + bflo(v5.x)) + (bflo(v6.x) + bflo(v7.x)));
        a1 += ((bfhi(v0.x) + bfhi(v1.x)) + (bfhi(v2.x) + bfhi(v3.x)))
            + ((bfhi(v4.x) + bfhi(v5.x)) + (bfhi(v6.x) + bfhi(v7.x)));
        a2 += ((bflo(v0.y) + bflo(v1.y)) + (bflo(v2.y) + bflo(v3.y)))
            + ((bflo(v4.y) + bflo(v5.y)) + (bflo(v6.y) + bflo(v7.y)));
        a3 += ((bfhi(v0.y) + bfhi(v1.y)) + (bfhi(v2.y) + bfhi(v3.y)))
            + ((bfhi(v4.y) + bfhi(v5.y)) + (bfhi(v6.y) + bfhi(v7.y)));
    }
    for (; k + 1 < e; k += 2) {
        int i0 = csr_src[k], i1 = csr_src[k + 1];
        uint2 v0 = *(const uint2*)(hc + (size_t)i0 * 128);
        uint2 v1 = *(const uint2*)(hc + (size_t)i1 * 128);
        a0 += bflo(v0.x) + bflo(v1.x);
        a1 += bfhi(v0.x) + bfhi(v1.x);
        a2 += bflo(v0.y) + bflo(v1.y);
        a3 += bfhi(v0.y) + bfhi(v1.y);
    }
    if (k < e) {
        int i0 = csr_src[k];
        uint2 v0 = *(const uint2*)(hc + (size_t)i0 * 128);
        a0 += bflo(v0.x); a1 += bfhi(v0.x);
        a2 += bflo(v0.y); a3 += bfhi(v0.y);
    }
    __syncthreads();

    float p0 = __shfl_xor(a0, 1, 64);
    float p1 = __shfl_xor(a1, 1, 64);
    float p2 = __shfl_xor(a2, 1, 64);
    float p3 = __shfl_xor(a3, 1, 64);
    float z[8];
    z[fh * 4 + 0] = a0; z[fh * 4 + 1] = a1; z[fh * 4 + 2] = a2; z[fh * 4 + 3] = a3;
    z[(1 - fh) * 4 + 0] = p0; z[(1 - fh) * 4 + 1] = p1;
    z[(1 - fh) * 4 + 2] = p2; z[(1 - fh) * 4 + 3] = p3;

    float o[8];
    #pragma unroll
    for (int f = 0; f < 8; f++) o[f] = sb2[f];
    #pragma unroll
    for (int j = 0; j < 16; j++) {
        float s1 = sb1[j];
        #pragma unroll
        for (int i2 = 0; i2 < 8; i2++) s1 += z[i2] * sW1[i2 * 16 + j];
        s1 = s1 * BN_SCALE * sg1[j] + sbt1[j];
        s1 = gelu_erf(s1);
        #pragma unroll
        for (int f = 0; f < 8; f++) o[f] += s1 * sW2[j * 8 + f];
    }
    float hv[8];
    #pragma unroll
    for (int f = 0; f < 8; f++)
        hv[f] = gelu_erf(o[f] * BN_SCALE * sg2[f] + sbt2[f]);

    // readout
    float q = 0.0f;
    #pragma unroll
    for (int j = 0; j < 8; j++) {
        float key = sbk[j];
        #pragma unroll
        for (int i2 = 0; i2 < 8; i2++) key += hv[i2] * sWk[i2 * 8 + j];
        q += key * sWq[j];
    }
    float w = sigmoidf_(q);
    if (fh == 0) w_out[(size_t)b * NGENES + g] = w;

    float contrib[8];
    #pragma unroll
    for (int f = 0; f < 8; f++) {
        float v = sbv[f];
        #pragma unroll
        for (int i2 = 0; i2 < 8; i2++) v += hv[i2] * sWv[i2 * 8 + f];
        contrib[f] = v * w;
    }
    // reduce over the 8 genes within each wave (gene stride = 8 lanes)
    #pragma unroll
    for (int f = 0; f < 8; f++) {
        contrib[f] += __shfl_xor(contrib[f], 8, 64);
        contrib[f] += __shfl_xor(contrib[f], 16, 64);
        contrib[f] += __shfl_xor(contrib[f], 32, 64);
    }
    int wave = t >> 6, lane = t & 63;
    if (lane < 8 && !(lane & 1)) {   // lane = sub (gene0), even half only
        #pragma unroll
        for (int f = 0; f < 8; f++) sRed[wave][lane >> 1][f] = contrib[f];
    }
    __syncthreads();
    if (t < 32) {
        int bl = t >> 3, f = t & 7;
        float sm = sRed[0][bl][f] + sRed[1][bl][f] + sRed[2][bl][f] + sRed[3][bl][f];
        atomicAdd(&g_h[(chunk * 4 + bl) * 8 + f], sm);
    }
}

// ---------------------------------------------------------------------------
__global__ __launch_bounds__(1024) void k_head(const float* __restrict__ g_h,
                                               const float* __restrict__ Wp1, const float* __restrict__ bp1,
                                               const float* __restrict__ gp1, const float* __restrict__ btp1,
                                               const float* __restrict__ Wp2, const float* __restrict__ bp2,
                                               const float* __restrict__ gp2, const float* __restrict__ btp2,
                                               const float* __restrict__ Wp3, const float* __restrict__ bp3,
                                               float* __restrict__ preds) {
    __shared__ float sgh[128];
    __shared__ float z1[16 * 64];
    __shared__ float z2[16 * 16];
    int t = threadIdx.x;
    if (t < 128) sgh[t] = g_h[t];
    __syncthreads();
    {
        int b = t >> 6, j = t & 63;
        float s = bp1[j];
        #pragma unroll
        for (int k = 0; k < 8; k++) s += sgh[b * 8 + k] * Wp1[k * 64 + j];
        s = s * BN_SCALE * gp1[j] + btp1[j];
        z1[b * 64 + j] = gelu_erf(s);
    }
    __syncthreads();
    if (t < 256) {
        int b = t >> 4, j = t & 15;
        float s = bp2[j];
        for (int k = 0; k < 64; k++) s += z1[b * 64 + k] * Wp2[k * 16 + j];
        s = s * BN_SCALE * gp2[j] + btp2[j];
        z2[b * 16 + j] = gelu_erf(s);
    }
    __syncthreads();
    if (t < 16) {
        float s = bp3[0];
        #pragma unroll
        for (int k = 0; k < 16; k++) s += z2[t * 16 + k] * Wp3[k];
        preds[t] = s;
    }
}

// ---------------------------------------------------------------------------
extern "C" void kernel_launch(void* const* d_in, const int* in_sizes, int n_in,
                              void* d_out, int out_size, void* d_ws, size_t ws_size,
                              hipStream_t stream) {
    const float* snp          = (const float*)d_in[0];
    const int*   snp_ids      = (const int*)  d_in[1];
    const int*   gene_of_node = (const int*)  d_in[2];
    const int*   edge_src     = (const int*)  d_in[3];
    const int*   edge_dst     = (const int*)  d_in[4];
    const float* filters      = (const float*)d_in[5];
    const float* eps          = (const float*)d_in[6];
    const float* W1  = (const float*)d_in[7];
    const float* b1  = (const float*)d_in[8];
    const float* g1  = (const float*)d_in[9];
    const float* bt1 = (const float*)d_in[10];
    const float* W2  = (const float*)d_in[11];
    const float* b2  = (const float*)d_in[12];
    const float* g2  = (const float*)d_in[13];
    const float* bt2 = (const float*)d_in[14];
    const float* Wk  = (const float*)d_in[15];
    const float* bk  = (const float*)d_in[16];
    const float* Wq  = (const float*)d_in[17];
    const float* Wv  = (const float*)d_in[18];
    const float* bv  = (const float*)d_in[19];
    const float* Wp1 = (const float*)d_in[20];
    const float* bp1 = (const float*)d_in[21];
    const float* gp1 = (const float*)d_in[22];
    const float* btp1= (const float*)d_in[23];
    const float* Wp2 = (const float*)d_in[24];
    const float* bp2 = (const float*)d_in[25];
    const float* gp2 = (const float*)d_in[26];
    const float* btp2= (const float*)d_in[27];
    const float* Wp3 = (const float*)d_in[28];
    const float* bp3 = (const float*)d_in[29];

    float* out        = (float*)d_out;
    float* out_preds  = out;
    float* out_filt   = out + 16;
    float* out_w      = out + 16 + NFILT * NSNPS;

    // ---- workspace layout
    char* ws = (char*)d_ws;
    size_t off = 0;
    u16* snpT = (u16*)(ws + off); off += (size_t)NSNPS * 16 * 2;                 // 16 MB
    u16* filtT= (u16*)(ws + off); off += (size_t)NSNPS * 8 * 2;                  // 8 MB
    u16* h0   = (u16*)(ws + off); off += (size_t)NGENES * 128 * 2;               // 5.12 MB
    u16* h1   = (u16*)(ws + off); off += (size_t)NGENES * 128 * 2;               // 5.12 MB
    int* node_off = (int*)(ws + off); off += ((NGENES + 1) * 4 + 255) / 256 * 256;
    int* deg      = (int*)(ws + off); off += (NGENES * 4 + 255) / 256 * 256;
    int* csr_off  = (int*)(ws + off); off += ((NGENES + 1) * 4 + 255) / 256 * 256;
    int* cursor   = (int*)(ws + off); off += (NGENES * 4 + 255) / 256 * 256;
    int* csr_src  = (int*)(ws + off); off += (size_t)NEDGES * 4;
    float* g_h    = (float*)(ws + off); off += 256;

    // 1. fused prep (filtersT + fp32 copy, snpT, node_off + zeroing)
    k_prep<<<PREP_NA + PREP_NB + PREP_NC, 256, 0, stream>>>(
        snp, filters, gene_of_node, snpT, filtT, out_filt, node_off, deg, g_h);
    // 2. CSR build
    k_deg<<<(NEDGES + 255) / 256, 256, 0, stream>>>(edge_dst, deg);
    k_scan<<<1, 1024, 0, stream>>>(deg, csr_off, cursor);
    k_scatter<<<(NEDGES + 255) / 256, 256, 0, stream>>>(edge_src, edge_dst, cursor, csr_src);
    // 3. SNP -> gene readout
    k_snp2gene<<<NGENES / 2, 256, 0, stream>>>(snpT, snp_ids, node_off, filtT, h0);
    // 4. GIN layer 1 (fused agg+MLP)
    k_gin1<<<(NGENES / 32) * 4, 256, 0, stream>>>(h0, h1, csr_off, csr_src, eps + 0,
                                                  W1 + 0 * 128, b1 + 0 * 16, g1 + 0 * 16, bt1 + 0 * 16,
                                                  W2 + 0 * 128, b2 + 0 * 8, g2 + 0 * 8, bt2 + 0 * 8);
    // 5. GIN layer 2 + attentive readout (fused)
    k_gin2<<<(NGENES / 32) * 4, 256, 0, stream>>>(h1, csr_off, csr_src, eps + 1,
                                                  W1 + 1 * 128, b1 + 1 * 16, g1 + 1 * 16, bt1 + 1 * 16,
                                                  W2 + 1 * 128, b2 + 1 * 8, g2 + 1 * 8, bt2 + 1 * 8,
                                                  Wk, bk, Wq, Wv, bv, out_w, g_h);
    // 6. head MLP
    k_head<<<1, 1024, 0, stream>>>(g_h, Wp1, bp1, gp1, btp1, Wp2, bp2, gp2, btp2, Wp3, bp3, out_preds);
}

// Round 8
// 334.029 us; speedup vs baseline: 1.5778x; 1.0633x over previous
//
#include <hip/hip_runtime.h>
#include <math.h>

#define NSNPS  500000
#define NGENES 20000
#define NNODES 600000
#define NEDGES 320000
#define BB     16
#define NFILT  8
#define NBLK2  2500   // k_gin2 grid = (NGENES/32)*4

// rsqrt(1 + 1e-5)
#define BN_SCALE 0.99999500003749968f

typedef unsigned short u16;

__device__ __forceinline__ float gelu_erf(float x) {
    return 0.5f * x * (1.0f + erff(x * 0.70710678118654752f));
}
__device__ __forceinline__ float sigmoidf_(float x) {
    return 1.0f / (1.0f + expf(-x));
}
// fp32 -> bf16 round-to-nearest-even
__device__ __forceinline__ u16 f2bf(float x) {
    unsigned u = __float_as_uint(x);
    u += 0x7fffu + ((u >> 16) & 1u);
    return (u16)(u >> 16);
}
__device__ __forceinline__ float bf1(u16 v)      { return __uint_as_float(((unsigned)v) << 16); }
__device__ __forceinline__ float bflo(unsigned v){ return __uint_as_float(v << 16); }
__device__ __forceinline__ float bfhi(unsigned v){ return __uint_as_float(v & 0xffff0000u); }
__device__ __forceinline__ unsigned pack2(float a, float b) {
    return (unsigned)f2bf(a) | ((unsigned)f2bf(b) << 16);
}

// ---------------------------------------------------------------------------
// Fused prep:
//  [A] filtersT bf16 + fp32 filters passthrough copy (one read of filters)
//  [B] snpT bf16
//  [C] node_off binary search + zero deg
#define PREP_NA 1954   // ceil(NSNPS/256)
#define PREP_NB 1954
#define PREP_NC 79     // ceil((NGENES+1)/256)
__global__ __launch_bounds__(256) void k_prep(const float* __restrict__ snp,
                                              const float* __restrict__ filters,
                                              const int* __restrict__ gene_of_node,
                                              u16* __restrict__ snpT,
                                              u16* __restrict__ filtT,
                                              float* __restrict__ out_filt,
                                              int* __restrict__ node_off,
                                              int* __restrict__ deg) {
    int bid = blockIdx.x;
    int t = threadIdx.x;
    if (bid < PREP_NA) {
        int n = bid * 256 + t;
        if (n < NSNPS) {
            float f0 = filters[0 * NSNPS + n], f1 = filters[1 * NSNPS + n];
            float f2 = filters[2 * NSNPS + n], f3 = filters[3 * NSNPS + n];
            float f4 = filters[4 * NSNPS + n], f5 = filters[5 * NSNPS + n];
            float f6 = filters[6 * NSNPS + n], f7 = filters[7 * NSNPS + n];
            uint4 p;
            p.x = pack2(f0, f1); p.y = pack2(f2, f3);
            p.z = pack2(f4, f5); p.w = pack2(f6, f7);
            *(uint4*)(filtT + (size_t)n * 8) = p;
            out_filt[0 * NSNPS + n] = f0; out_filt[1 * NSNPS + n] = f1;
            out_filt[2 * NSNPS + n] = f2; out_filt[3 * NSNPS + n] = f3;
            out_filt[4 * NSNPS + n] = f4; out_filt[5 * NSNPS + n] = f5;
            out_filt[6 * NSNPS + n] = f6; out_filt[7 * NSNPS + n] = f7;
        }
    } else if (bid < PREP_NA + PREP_NB) {
        int n = (bid - PREP_NA) * 256 + t;
        if (n < NSNPS) {
            uint4 p0, p1;
            p0.x = pack2(snp[0 * (size_t)NSNPS + n],  snp[1 * (size_t)NSNPS + n]);
            p0.y = pack2(snp[2 * (size_t)NSNPS + n],  snp[3 * (size_t)NSNPS + n]);
            p0.z = pack2(snp[4 * (size_t)NSNPS + n],  snp[5 * (size_t)NSNPS + n]);
            p0.w = pack2(snp[6 * (size_t)NSNPS + n],  snp[7 * (size_t)NSNPS + n]);
            p1.x = pack2(snp[8 * (size_t)NSNPS + n],  snp[9 * (size_t)NSNPS + n]);
            p1.y = pack2(snp[10 * (size_t)NSNPS + n], snp[11 * (size_t)NSNPS + n]);
            p1.z = pack2(snp[12 * (size_t)NSNPS + n], snp[13 * (size_t)NSNPS + n]);
            p1.w = pack2(snp[14 * (size_t)NSNPS + n], snp[15 * (size_t)NSNPS + n]);
            uint4* dst = (uint4*)(snpT + (size_t)n * 16);
            dst[0] = p0; dst[1] = p1;
        }
    } else {
        int g = (bid - PREP_NA - PREP_NB) * 256 + t;
        if (g < NGENES) deg[g] = 0;
        if (g <= NGENES) {
            int lo = 0, hi = NNODES;
            while (lo < hi) {
                int mid = (lo + hi) >> 1;
                if (gene_of_node[mid] < g) lo = mid + 1; else hi = mid;
            }
            node_off[g] = lo;
        }
    }
}

// ---------------------------------------------------------------------------
__global__ __launch_bounds__(256) void k_deg(const int* __restrict__ edge_dst,
                                             int* __restrict__ deg) {
    int e = blockIdx.x * 256 + threadIdx.x;
    if (e >= NEDGES) return;
    atomicAdd(&deg[edge_dst[e]], 1);
}

__global__ __launch_bounds__(1024) void k_scan(const int* __restrict__ deg,
                                               int* __restrict__ csr_off,
                                               int* __restrict__ cursor) {
    __shared__ int sums[1024];
    int t = threadIdx.x;
    const int CH = (NGENES + 1023) / 1024;   // 20
    int base = t * CH;
    int s = 0;
    for (int i = 0; i < CH; i++) {
        int idx = base + i;
        if (idx < NGENES) s += deg[idx];
    }
    sums[t] = s;
    __syncthreads();
    for (int off = 1; off < 1024; off <<= 1) {
        int v = (t >= off) ? sums[t - off] : 0;
        __syncthreads();
        sums[t] += v;
        __syncthreads();
    }
    int run = (t == 0) ? 0 : sums[t - 1];
    for (int i = 0; i < CH; i++) {
        int idx = base + i;
        if (idx < NGENES) {
            csr_off[idx] = run;
            cursor[idx]  = run;
            run += deg[idx];
        }
    }
    if (t == 1023) csr_off[NGENES] = sums[1023];
}

__global__ __launch_bounds__(256) void k_scatter(const int* __restrict__ edge_src,
                                                 const int* __restrict__ edge_dst,
                                                 int* __restrict__ cursor,
                                                 int* __restrict__ csr_src) {
    int e = blockIdx.x * 256 + threadIdx.x;
    if (e >= NEDGES) return;
    int p = atomicAdd(&cursor[edge_dst[e]], 1);
    csr_src[p] = edge_src[e];
}

// ---------------------------------------------------------------------------
// SNP->gene (bf16): TWO waves per gene, 2 genes per block. lane = sub4*16 + b.
__global__ __launch_bounds__(256) void k_snp2gene(const u16* __restrict__ snpT,
                                                  const int* __restrict__ snp_ids,
                                                  const int* __restrict__ node_off,
                                                  const u16* __restrict__ filtT,
                                                  u16* __restrict__ h_bf) {
    __shared__ float sZ[2][2][128];
    int t = threadIdx.x;
    int waveIdx = t >> 6, lane = t & 63;
    int gidx = waveIdx >> 1;
    int pair = waveIdx & 1;
    int g = blockIdx.x * 2 + gidx;
    int sub = (pair << 2) + (lane >> 4);     // 0..7
    int b = lane & 15;
    int s = node_off[g], e = node_off[g + 1];

    float acc[8];
    #pragma unroll
    for (int f = 0; f < 8; f++) acc[f] = 0.0f;

    int i = s + sub;
    for (; i + 24 < e; i += 32) {
        int id0 = snp_ids[i];
        int id1 = snp_ids[i + 8];
        int id2 = snp_ids[i + 16];
        int id3 = snp_ids[i + 24];
        float v0 = bf1(snpT[(size_t)id0 * 16 + b]);
        float v1 = bf1(snpT[(size_t)id1 * 16 + b]);
        float v2 = bf1(snpT[(size_t)id2 * 16 + b]);
        float v3 = bf1(snpT[(size_t)id3 * 16 + b]);
        uint4 F0 = *(const uint4*)(filtT + (size_t)id0 * 8);
        uint4 F1 = *(const uint4*)(filtT + (size_t)id1 * 8);
        uint4 F2 = *(const uint4*)(filtT + (size_t)id2 * 8);
        uint4 F3 = *(const uint4*)(filtT + (size_t)id3 * 8);
        acc[0] += v0 * bflo(F0.x) + v1 * bflo(F1.x) + v2 * bflo(F2.x) + v3 * bflo(F3.x);
        acc[1] += v0 * bfhi(F0.x) + v1 * bfhi(F1.x) + v2 * bfhi(F2.x) + v3 * bfhi(F3.x);
        acc[2] += v0 * bflo(F0.y) + v1 * bflo(F1.y) + v2 * bflo(F2.y) + v3 * bflo(F3.y);
        acc[3] += v0 * bfhi(F0.y) + v1 * bfhi(F1.y) + v2 * bfhi(F2.y) + v3 * bfhi(F3.y);
        acc[4] += v0 * bflo(F0.z) + v1 * bflo(F1.z) + v2 * bflo(F2.z) + v3 * bflo(F3.z);
        acc[5] += v0 * bfhi(F0.z) + v1 * bfhi(F1.z) + v2 * bfhi(F2.z) + v3 * bfhi(F3.z);
        acc[6] += v0 * bflo(F0.w) + v1 * bflo(F1.w) + v2 * bflo(F2.w) + v3 * bflo(F3.w);
        acc[7] += v0 * bfhi(F0.w) + v1 * bfhi(F1.w) + v2 * bfhi(F2.w) + v3 * bfhi(F3.w);
    }
    for (; i + 8 < e; i += 16) {
        int id0 = snp_ids[i];
        int id1 = snp_ids[i + 8];
        float v0 = bf1(snpT[(size_t)id0 * 16 + b]);
        float v1 = bf1(snpT[(size_t)id1 * 16 + b]);
        uint4 F0 = *(const uint4*)(filtT + (size_t)id0 * 8);
        uint4 F1 = *(const uint4*)(filtT + (size_t)id1 * 8);
        acc[0] += v0 * bflo(F0.x) + v1 * bflo(F1.x);
        acc[1] += v0 * bfhi(F0.x) + v1 * bfhi(F1.x);
        acc[2] += v0 * bflo(F0.y) + v1 * bflo(F1.y);
        acc[3] += v0 * bfhi(F0.y) + v1 * bfhi(F1.y);
        acc[4] += v0 * bflo(F0.z) + v1 * bflo(F1.z);
        acc[5] += v0 * bfhi(F0.z) + v1 * bfhi(F1.z);
        acc[6] += v0 * bflo(F0.w) + v1 * bflo(F1.w);
        acc[7] += v0 * bfhi(F0.w) + v1 * bfhi(F1.w);
    }
    if (i < e) {
        int id0 = snp_ids[i];
        float v0 = bf1(snpT[(size_t)id0 * 16 + b]);
        uint4 F0 = *(const uint4*)(filtT + (size_t)id0 * 8);
        acc[0] += v0 * bflo(F0.x); acc[1] += v0 * bfhi(F0.x);
        acc[2] += v0 * bflo(F0.y); acc[3] += v0 * bfhi(F0.y);
        acc[4] += v0 * bflo(F0.z); acc[5] += v0 * bfhi(F0.z);
        acc[6] += v0 * bflo(F0.w); acc[7] += v0 * bfhi(F0.w);
    }
    #pragma unroll
    for (int f = 0; f < 8; f++) {
        acc[f] += __shfl_xor(acc[f], 16, 64);
        acc[f] += __shfl_xor(acc[f], 32, 64);
    }
    if (lane < 16) {
        float* dst = &sZ[gidx][pair][lane * 8];
        *(float4*)(dst)     = make_float4(acc[0], acc[1], acc[2], acc[3]);
        *(float4*)(dst + 4) = make_float4(acc[4], acc[5], acc[6], acc[7]);
    }
    __syncthreads();
    {
        int half = t >> 7;
        int c = t & 127;
        int gg = blockIdx.x * 2 + half;
        float val = sZ[half][0][c] + sZ[half][1][c];
        h_bf[(size_t)gg * 128 + c] = f2bf(val);
    }
}

// ---------------------------------------------------------------------------
// Fused GIN layer 1: chunked agg (bf16, L2-resident slice) + split-j MLP.
// Block = 32 genes x 8 subs; chunk = blockIdx&3. Pair threads (t, t^1) hold
// the two f-halves of one (g,b) row; each computes 8 of the 16 hidden units.
__global__ __launch_bounds__(256) void k_gin1(const u16* __restrict__ hin,   // [g][128]
                                              u16* __restrict__ hout,        // [g][128]
                                              const int* __restrict__ csr_off,
                                              const int* __restrict__ csr_src,
                                              const float* __restrict__ eps_l,
                                              const float* __restrict__ W1,
                                              const float* __restrict__ b1,
                                              const float* __restrict__ g1,
                                              const float* __restrict__ bt1,
                                              const float* __restrict__ W2,
                                              const float* __restrict__ b2,
                                              const float* __restrict__ g2,
                                              const float* __restrict__ bt2) {
    __shared__ float sW1[128], sb1[16], sg1[16], sbt1[16];
    __shared__ float sW2[128], sb2[8], sg2[8], sbt2[8];
    int t = threadIdx.x;
    if (t < 128) { sW1[t] = W1[t]; sW2[t] = W2[t]; }
    if (t < 16)  { sb1[t] = b1[t]; sg1[t] = g1[t]; sbt1[t] = bt1[t]; }
    if (t < 8)   { sb2[t] = b2[t]; sg2[t] = g2[t]; sbt2[t] = bt2[t]; }

    int chunk = blockIdx.x & 3;
    int g = (blockIdx.x >> 2) * 32 + (t >> 3);
    int col = chunk * 32 + (t & 7) * 4;
    int fh = (t & 7) & 1;                    // f-half: 0 -> f0..3, 1 -> f4..7
    const u16* __restrict__ hc = hin + col;
    float epsv = 1.0f + eps_l[0];

    uint2 su = *(const uint2*)(hc + (size_t)g * 128);
    float a0 = bflo(su.x) * epsv, a1 = bfhi(su.x) * epsv;
    float a2 = bflo(su.y) * epsv, a3 = bfhi(su.y) * epsv;

    int s = csr_off[g], e = csr_off[g + 1];
    int k = s;
    for (; k + 7 < e; k += 8) {
        int i0 = csr_src[k],     i1 = csr_src[k + 1];
        int i2 = csr_src[k + 2], i3 = csr_src[k + 3];
        int i4 = csr_src[k + 4], i5 = csr_src[k + 5];
        int i6 = csr_src[k + 6], i7 = csr_src[k + 7];
        uint2 v0 = *(const uint2*)(hc + (size_t)i0 * 128);
        uint2 v1 = *(const uint2*)(hc + (size_t)i1 * 128);
        uint2 v2 = *(const uint2*)(hc + (size_t)i2 * 128);
        uint2 v3 = *(const uint2*)(hc + (size_t)i3 * 128);
        uint2 v4 = *(const uint2*)(hc + (size_t)i4 * 128);
        uint2 v5 = *(const uint2*)(hc + (size_t)i5 * 128);
        uint2 v6 = *(const uint2*)(hc + (size_t)i6 * 128);
        uint2 v7 = *(const uint2*)(hc + (size_t)i7 * 128);
        a0 += ((bflo(v0.x) + bflo(v1.x)) + (bflo(v2.x) + bflo(v3.x)))
            + ((bflo(v4.x) + bflo(v5.x)) + (bflo(v6.x) + bflo(v7.x)));
        a1 += ((bfhi(v0.x) + bfhi(v1.x)) + (bfhi(v2.x) + bfhi(v3.x)))
            + ((bfhi(v4.x) + bfhi(v5.x)) + (bfhi(v6.x) + bfhi(v7.x)));
        a2 += ((bflo(v0.y) + bflo(v1.y)) + (bflo(v2.y) + bflo(v3.y)))
            + ((bflo(v4.y) + bflo(v5.y)) + (bflo(v6.y) + bflo(v7.y)));
        a3 += ((bfhi(v0.y) + bfhi(v1.y)) + (bfhi(v2.y) + bfhi(v3.y)))
            + ((bfhi(v4.y) + bfhi(v5.y)) + (bfhi(v6.y) + bfhi(v7.y)));
    }
    for (; k + 1 < e; k += 2) {
        int i0 = csr_src[k], i1 = csr_src[k + 1];
        uint2 v0 = *(const uint2*)(hc + (size_t)i0 * 128);
        uint2 v1 = *(const uint2*)(hc + (size_t)i1 * 128);
        a0 += bflo(v0.x) + bflo(v1.x);
        a1 += bfhi(v0.x) + bfhi(v1.x);
        a2 += bflo(v0.y) + bflo(v1.y);
        a3 += bfhi(v0.y) + bfhi(v1.y);
    }
    if (k < e) {
        int i0 = csr_src[k];
        uint2 v0 = *(const uint2*)(hc + (size_t)i0 * 128);
        a0 += bflo(v0.x); a1 += bfhi(v0.x);
        a2 += bflo(v0.y); a3 += bfhi(v0.y);
    }
    __syncthreads();   // weights visible

    // exchange halves with the pair thread (same gene, same batch)
    float p0 = __shfl_xor(a0, 1, 64);
    float p1 = __shfl_xor(a1, 1, 64);
    float p2 = __shfl_xor(a2, 1, 64);
    float p3 = __shfl_xor(a3, 1, 64);
    float z[8];
    z[fh * 4 + 0] = a0; z[fh * 4 + 1] = a1; z[fh * 4 + 2] = a2; z[fh * 4 + 3] = a3;
    z[(1 - fh) * 4 + 0] = p0; z[(1 - fh) * 4 + 1] = p1;
    z[(1 - fh) * 4 + 2] = p2; z[(1 - fh) * 4 + 3] = p3;

    // split-j MLP: this thread handles hidden units j in [fh*8, fh*8+8)
    float op[8];
    #pragma unroll
    for (int f = 0; f < 8; f++) op[f] = (fh == 0) ? sb2[f] : 0.0f;
    #pragma unroll
    for (int jj = 0; jj < 8; jj++) {
        int j = fh * 8 + jj;
        float s1 = sb1[j];
        #pragma unroll
        for (int i2 = 0; i2 < 8; i2++) s1 += z[i2] * sW1[i2 * 16 + j];
        s1 = s1 * BN_SCALE * sg1[j] + sbt1[j];
        s1 = gelu_erf(s1);
        #pragma unroll
        for (int f = 0; f < 8; f++) op[f] += s1 * sW2[j * 8 + f];
    }
    // combine partial outputs, then each thread finalizes its 4 f's
    float r[4];
    #pragma unroll
    for (int fi = 0; fi < 4; fi++) {
        int f = fh * 4 + fi;
        float of = op[f] + __shfl_xor(op[f], 1, 64);
        r[fi] = gelu_erf(of * BN_SCALE * sg2[f] + sbt2[f]);
    }
    uint2 ou;
    ou.x = pack2(r[0], r[1]); ou.y = pack2(r[2], r[3]);
    *(uint2*)(hout + (size_t)g * 128 + col) = ou;
}

// ---------------------------------------------------------------------------
// Fused GIN layer 2 + attentive readout. No atomics: per-block partial sums
// stored to partial[block][32] (4 batches x 8 filters), reduced in k_head.
__global__ __launch_bounds__(256) void k_gin2(const u16* __restrict__ hin,
                                              const int* __restrict__ csr_off,
                                              const int* __restrict__ csr_src,
                                              const float* __restrict__ eps_l,
                                              const float* __restrict__ W1,
                                              const float* __restrict__ b1,
                                              const float* __restrict__ g1,
                                              const float* __restrict__ bt1,
                                              const float* __restrict__ W2,
                                              const float* __restrict__ b2,
                                              const float* __restrict__ g2,
                                              const float* __restrict__ bt2,
                                              const float* __restrict__ Wk,
                                              const float* __restrict__ bk,
                                              const float* __restrict__ Wq,
                                              const float* __restrict__ Wv,
                                              const float* __restrict__ bv,
                                              float* __restrict__ w_out,    // [b][g]
                                              float* __restrict__ partial) { // [NBLK2][32]
    __shared__ float sW1[128], sb1[16], sg1[16], sbt1[16];
    __shared__ float sW2[128], sb2[8], sg2[8], sbt2[8];
    __shared__ float sWk[64], sWv[64], sbk[8], sbv[8], sWq[8];
    __shared__ float sRed[4][4][8];
    int t = threadIdx.x;
    if (t < 128) { sW1[t] = W1[t]; sW2[t] = W2[t]; }
    if (t < 64)  { sWk[t] = Wk[t]; sWv[t] = Wv[t]; }
    if (t < 16)  { sb1[t] = b1[t]; sg1[t] = g1[t]; sbt1[t] = bt1[t]; }
    if (t < 8)   { sb2[t] = b2[t]; sg2[t] = g2[t]; sbt2[t] = bt2[t];
                   sbk[t] = bk[t]; sbv[t] = bv[t]; sWq[t] = Wq[t]; }

    int chunk = blockIdx.x & 3;
    int g = (blockIdx.x >> 2) * 32 + (t >> 3);
    int col = chunk * 32 + (t & 7) * 4;
    int fh = (t & 7) & 1;
    int b = chunk * 4 + ((t & 7) >> 1);      // global batch for this row
    const u16* __restrict__ hc = hin + col;
    float epsv = 1.0f + eps_l[0];

    uint2 su = *(const uint2*)(hc + (size_t)g * 128);
    float a0 = bflo(su.x) * epsv, a1 = bfhi(su.x) * epsv;
    float a2 = bflo(su.y) * epsv, a3 = bfhi(su.y) * epsv;

    int s = csr_off[g], e = csr_off[g + 1];
    int k = s;
    for (; k + 7 < e; k += 8) {
        int i0 = csr_src[k],     i1 = csr_src[k + 1];
        int i2 = csr_src[k + 2], i3 = csr_src[k + 3];
        int i4 = csr_src[k + 4], i5 = csr_src[k + 5];
        int i6 = csr_src[k + 6], i7 = csr_src[k + 7];
        uint2 v0 = *(const uint2*)(hc + (size_t)i0 * 128);
        uint2 v1 = *(const uint2*)(hc + (size_t)i1 * 128);
        uint2 v2 = *(const uint2*)(hc + (size_t)i2 * 128);
        uint2 v3 = *(const uint2*)(hc + (size_t)i3 * 128);
        uint2 v4 = *(const uint2*)(hc + (size_t)i4 * 128);
        uint2 v5 = *(const uint2*)(hc + (size_t)i5 * 128);
        uint2 v6 = *(const uint2*)(hc + (size_t)i6 * 128);
        uint2 v7 = *(const uint2*)(hc + (size_t)i7 * 128);
        a0 += ((bflo(v0.x) + bflo(v1.x)) + (bflo(v2.x) + bflo(v3.x)))
            + ((bflo(v4.x) + bflo(v5.x)) + (bflo(v6.x) + bflo(v7.x)));
        a1 += ((bfhi(v0.x) + bfhi(v1.x)) + (bfhi(v2.x) + bfhi(v3.x)))
            + ((bfhi(v4.x) + bfhi(v5.x)) + (bfhi(v6.x) + bfhi(v7.x)));
        a2 += ((bflo(v0.y) + bflo(v1.y)) + (bflo(v2.y) + bflo(v3.y)))
            + ((bflo(v4.y) + bflo(v5.y)) + (bflo(v6.y) + bflo(v7.y)));
        a3 += ((bfhi(v0.y) + bfhi(v1.y)) + (bfhi(v2.y) + bfhi(v3.y)))
            + ((bfhi(v4.y) + bfhi(v5.y)) + (bfhi(v6.y) + bfhi(v7.y)));
    }
    for (; k + 1 < e; k += 2) {
        int i0 = csr_src[k], i1 = csr_src[k + 1];
        uint2 v0 = *(const uint2*)(hc + (size_t)i0 * 128);
        uint2 v1 = *(const uint2*)(hc + (size_t)i1 * 128);
        a0 += bflo(v0.x) + bflo(v1.x);
        a1 += bfhi(v0.x) + bfhi(v1.x);
        a2 += bflo(v0.y) + bflo(v1.y);
        a3 += bfhi(v0.y) + bfhi(v1.y);
    }
    if (k < e) {
        int i0 = csr_src[k];
        uint2 v0 = *(const uint2*)(hc + (size_t)i0 * 128);
        a0 += bflo(v0.x); a1 += bfhi(v0.x);
        a2 += bflo(v0.y); a3 += bfhi(v0.y);
    }
    __syncthreads();

    float p0 = __shfl_xor(a0, 1, 64);
    float p1 = __shfl_xor(a1, 1, 64);
    float p2 = __shfl_xor(a2, 1, 64);
    float p3 = __shfl_xor(a3, 1, 64);
    float z[8];
    z[fh * 4 + 0] = a0; z[fh * 4 + 1] = a1; z[fh * 4 + 2] = a2; z[fh * 4 + 3] = a3;
    z[(1 - fh) * 4 + 0] = p0; z[(1 - fh) * 4 + 1] = p1;
    z[(1 - fh) * 4 + 2] = p2; z[(1 - fh) * 4 + 3] = p3;

    // split-j MLP
    float op[8];
    #pragma unroll
    for (int f = 0; f < 8; f++) op[f] = (fh == 0) ? sb2[f] : 0.0f;
    #pragma unroll
    for (int jj = 0; jj < 8; jj++) {
        int j = fh * 8 + jj;
        float s1 = sb1[j];
        #pragma unroll
        for (int i2 = 0; i2 < 8; i2++) s1 += z[i2] * sW1[i2 * 16 + j];
        s1 = s1 * BN_SCALE * sg1[j] + sbt1[j];
        s1 = gelu_erf(s1);
        #pragma unroll
        for (int f = 0; f < 8; f++) op[f] += s1 * sW2[j * 8 + f];
    }
    // finalize own half of h, then exchange halves to get full hv[8]
    float hvh[4];
    #pragma unroll
    for (int fi = 0; fi < 4; fi++) {
        int f = fh * 4 + fi;
        float of = op[f] + __shfl_xor(op[f], 1, 64);
        hvh[fi] = gelu_erf(of * BN_SCALE * sg2[f] + sbt2[f]);
    }
    float hv[8];
    #pragma unroll
    for (int fi = 0; fi < 4; fi++) {
        hv[fh * 4 + fi] = hvh[fi];
        hv[(1 - fh) * 4 + fi] = __shfl_xor(hvh[fi], 1, 64);
    }

    // readout: q split over j-halves
    float qp = 0.0f;
    #pragma unroll
    for (int jj = 0; jj < 4; jj++) {
        int j = fh * 4 + jj;
        float key = sbk[j];
        #pragma unroll
        for (int i2 = 0; i2 < 8; i2++) key += hv[i2] * sWk[i2 * 8 + j];
        qp += key * sWq[j];
    }
    float q = qp + __shfl_xor(qp, 1, 64);
    float w = sigmoidf_(q);
    if (fh == 0) w_out[(size_t)b * NGENES + g] = w;

    // value contribution: own f-half only (no duplication)
    float contrib[4];
    #pragma unroll
    for (int fi = 0; fi < 4; fi++) {
        int f = fh * 4 + fi;
        float v = sbv[f];
        #pragma unroll
        for (int i2 = 0; i2 < 8; i2++) v += hv[i2] * sWv[i2 * 8 + f];
        contrib[fi] = v * w;
    }
    // reduce over the 8 genes within each wave (gene stride = 8 lanes)
    #pragma unroll
    for (int fi = 0; fi < 4; fi++) {
        contrib[fi] += __shfl_xor(contrib[fi], 8, 64);
        contrib[fi] += __shfl_xor(contrib[fi], 16, 64);
        contrib[fi] += __shfl_xor(contrib[fi], 32, 64);
    }
    int wave = t >> 6, lane = t & 63;
    if (lane < 8) {
        #pragma unroll
        for (int fi = 0; fi < 4; fi++)
            sRed[wave][lane >> 1][(lane & 1) * 4 + fi] = contrib[fi];
    }
    __syncthreads();
    if (t < 32) {   // 4 local batches x 8 filters -> plain store (NO atomics)
        int bl = t >> 3, f = t & 7;
        float sm = sRed[0][bl][f] + sRed[1][bl][f] + sRed[2][bl][f] + sRed[3][bl][f];
        partial[(size_t)blockIdx.x * 32 + bl * 8 + f] = sm;
    }
}

// ---------------------------------------------------------------------------
// Head MLP. Phase 0 reduces the per-block readout partials (no atomics).
__global__ __launch_bounds__(1024) void k_head(const float* __restrict__ partial, // [NBLK2][32]
                                               const float* __restrict__ Wp1, const float* __restrict__ bp1,
                                               const float* __restrict__ gp1, const float* __restrict__ btp1,
                                               const float* __restrict__ Wp2, const float* __restrict__ bp2,
                                               const float* __restrict__ gp2, const float* __restrict__ btp2,
                                               const float* __restrict__ Wp3, const float* __restrict__ bp3,
                                               float* __restrict__ preds) {
    __shared__ float sgh[128];
    __shared__ float red[1024];
    __shared__ float z1[16 * 64];
    __shared__ float z2[16 * 16];
    int t = threadIdx.x;
    // phase 0: g_h[b*8+f] = sum over blocks with chunk == b>>2
    {
        int bf = t >> 3;            // 0..127 = b*8+f
        int ln = t & 7;
        int b = bf >> 3, f = bf & 7;
        int c = b >> 2, bl = b & 3;
        float s = 0.0f;
        for (int j = ln; j < NBLK2 / 4; j += 8)     // 625 blocks per chunk
            s += partial[(size_t)(c + 4 * j) * 32 + bl * 8 + f];
        red[t] = s;
    }
    __syncthreads();
    if ((t & 7) == 0) {
        int bf = t >> 3;
        float tot = 0.0f;
        #pragma unroll
        for (int k = 0; k < 8; k++) tot += red[(bf << 3) + k];
        sgh[bf] = tot;
    }
    __syncthreads();
    {
        int b = t >> 6, j = t & 63;
        float s = bp1[j];
        #pragma unroll
        for (int k = 0; k < 8; k++) s += sgh[b * 8 + k] * Wp1[k * 64 + j];
        s = s * BN_SCALE * gp1[j] + btp1[j];
        z1[b * 64 + j] = gelu_erf(s);
    }
    __syncthreads();
    if (t < 256) {
        int b = t >> 4, j = t & 15;
        float s = bp2[j];
        for (int k = 0; k < 64; k++) s += z1[b * 64 + k] * Wp2[k * 16 + j];
        s = s * BN_SCALE * gp2[j] + btp2[j];
        z2[b * 16 + j] = gelu_erf(s);
    }
    __syncthreads();
    if (t < 16) {
        float s = bp3[0];
        #pragma unroll
        for (int k = 0; k < 16; k++) s += z2[t * 16 + k] * Wp3[k];
        preds[t] = s;
    }
}

// ---------------------------------------------------------------------------
extern "C" void kernel_launch(void* const* d_in, const int* in_sizes, int n_in,
                              void* d_out, int out_size, void* d_ws, size_t ws_size,
                              hipStream_t stream) {
    const float* snp          = (const float*)d_in[0];
    const int*   snp_ids      = (const int*)  d_in[1];
    const int*   gene_of_node = (const int*)  d_in[2];
    const int*   edge_src     = (const int*)  d_in[3];
    const int*   edge_dst     = (const int*)  d_in[4];
    const float* filters      = (const float*)d_in[5];
    const float* eps          = (const float*)d_in[6];
    const float* W1  = (const float*)d_in[7];
    const float* b1  = (const float*)d_in[8];
    const float* g1  = (const float*)d_in[9];
    const float* bt1 = (const float*)d_in[10];
    const float* W2  = (const float*)d_in[11];
    const float* b2  = (const float*)d_in[12];
    const float* g2  = (const float*)d_in[13];
    const float* bt2 = (const float*)d_in[14];
    const float* Wk  = (const float*)d_in[15];
    const float* bk  = (const float*)d_in[16];
    const float* Wq  = (const float*)d_in[17];
    const float* Wv  = (const float*)d_in[18];
    const float* bv  = (const float*)d_in[19];
    const float* Wp1 = (const float*)d_in[20];
    const float* bp1 = (const float*)d_in[21];
    const float* gp1 = (const float*)d_in[22];
    const float* btp1= (const float*)d_in[23];
    const float* Wp2 = (const float*)d_in[24];
    const float* bp2 = (const float*)d_in[25];
    const float* gp2 = (const float*)d_in[26];
    const float* btp2= (const float*)d_in[27];
    const float* Wp3 = (const float*)d_in[28];
    const float* bp3 = (const float*)d_in[29];

    float* out        = (float*)d_out;
    float* out_preds  = out;
    float* out_filt   = out + 16;
    float* out_w      = out + 16 + NFILT * NSNPS;

    // ---- workspace layout
    char* ws = (char*)d_ws;
    size_t off = 0;
    u16* snpT = (u16*)(ws + off); off += (size_t)NSNPS * 16 * 2;                 // 16 MB
    u16* filtT= (u16*)(ws + off); off += (size_t)NSNPS * 8 * 2;                  // 8 MB
    u16* h0   = (u16*)(ws + off); off += (size_t)NGENES * 128 * 2;               // 5.12 MB
    u16* h1   = (u16*)(ws + off); off += (size_t)NGENES * 128 * 2;               // 5.12 MB
    int* node_off = (int*)(ws + off); off += ((NGENES + 1) * 4 + 255) / 256 * 256;
    int* deg      = (int*)(ws + off); off += (NGENES * 4 + 255) / 256 * 256;
    int* csr_off  = (int*)(ws + off); off += ((NGENES + 1) * 4 + 255) / 256 * 256;
    int* cursor   = (int*)(ws + off); off += (NGENES * 4 + 255) / 256 * 256;
    int* csr_src  = (int*)(ws + off); off += (size_t)NEDGES * 4;
    float* partial= (float*)(ws + off); off += (size_t)NBLK2 * 32 * 4;           // 320 KB

    // 1. fused prep (filtersT + fp32 copy, snpT, node_off + deg zeroing)
    k_prep<<<PREP_NA + PREP_NB + PREP_NC, 256, 0, stream>>>(
        snp, filters, gene_of_node, snpT, filtT, out_filt, node_off, deg);
    // 2. CSR build
    k_deg<<<(NEDGES + 255) / 256, 256, 0, stream>>>(edge_dst, deg);
    k_scan<<<1, 1024, 0, stream>>>(deg, csr_off, cursor);
    k_scatter<<<(NEDGES + 255) / 256, 256, 0, stream>>>(edge_src, edge_dst, cursor, csr_src);
    // 3. SNP -> gene readout
    k_snp2gene<<<NGENES / 2, 256, 0, stream>>>(snpT, snp_ids, node_off, filtT, h0);
    // 4. GIN layer 1 (fused agg + split-j MLP)
    k_gin1<<<NBLK2, 256, 0, stream>>>(h0, h1, csr_off, csr_src, eps + 0,
                                      W1 + 0 * 128, b1 + 0 * 16, g1 + 0 * 16, bt1 + 0 * 16,
                                      W2 + 0 * 128, b2 + 0 * 8, g2 + 0 * 8, bt2 + 0 * 8);
    // 5. GIN layer 2 + attentive readout (no atomics)
    k_gin2<<<NBLK2, 256, 0, stream>>>(h1, csr_off, csr_src, eps + 1,
                                      W1 + 1 * 128, b1 + 1 * 16, g1 + 1 * 16, bt1 + 1 * 16,
                                      W2 + 1 * 128, b2 + 1 * 8, g2 + 1 * 8, bt2 + 1 * 8,
                                      Wk, bk, Wq, Wv, bv, out_w, partial);
    // 6. head MLP (reduces partials in phase 0)
    k_head<<<1, 1024, 0, stream>>>(partial, Wp1, bp1, gp1, btp1, Wp2, bp2, gp2, btp2, Wp3, bp3, out_preds);
}